// Round 6
// baseline (443.952 us; speedup 1.0000x reference)
//
#include <hip/hip_runtime.h>
#include <math.h>

// Problem constants (fixed by setup_inputs)
#define BATCH 2
#define DIM   256
#define THW   8192            // T*H*W = 8*32*32
#define NTOK  16384           // BATCH*THW
#define KCB   8192            // codebook size
#define OUTQ  4194304         // BATCH*DIM*THW
#define CAP   2000000         // candidate buffer entries (16 MB in d_out)
#define SCAP  5600            // per-block LDS candidate staging capacity

typedef short short8 __attribute__((ext_vector_type(8)));
typedef float f32x4 __attribute__((ext_vector_type(4)));

__device__ __forceinline__ unsigned short f2bf_rn(float v) {
    unsigned u = __float_as_uint(v);
    unsigned r = u + 0x7FFFu + ((u >> 16) & 1u);
    return (unsigned short)(r >> 16);
}
__device__ __forceinline__ float bf2f(unsigned short b) {
    return __uint_as_float((unsigned)b << 16);
}
__device__ __forceinline__ void gl2lds16(const unsigned short* g, unsigned short* l) {
    __builtin_amdgcn_global_load_lds(
        (const __attribute__((address_space(1))) void*)g,
        (__attribute__((address_space(3))) void*)l, 16, 0, 0);
}

// ---------------------------------------------------------------------------
// buildA: z -> Ahi/Alo [NTOK][256]; zsq, sA=2.1*sqrt(zlosq), sB=2.1*sqrt(zsq);
// per-block per-dim partial sums of z -> partialZ[blk][256]
// ---------------------------------------------------------------------------
__global__ void k_buildA(const float* __restrict__ z,
                         unsigned short* __restrict__ Ahi,
                         unsigned short* __restrict__ Alo,
                         float* __restrict__ zsq,
                         float* __restrict__ sA, float* __restrict__ sB,
                         float* __restrict__ partialZ) {
    __shared__ ushort2 tile[64][65];
    __shared__ float zacc[64];
    __shared__ float lacc[64];
    __shared__ float pz[256];
    int t = threadIdx.x;
    int n0 = blockIdx.x * 64;
    int b = n0 >> 13;
    int thw0 = n0 & 8191;
    if (t < 64) { zacc[t] = 0.f; lacc[t] = 0.f; }
    pz[t] = 0.f;
    __syncthreads();
    int nn_r = t & 63, dg = t >> 6;
    float a1 = 0.f, a2 = 0.f;
    for (int dc = 0; dc < 256; dc += 64) {
        for (int r = 0; r < 16; ++r) {
            int dd = r * 4 + dg;
            float v = z[((size_t)(b * 256 + dc + dd)) * 8192 + thw0 + nn_r];
            unsigned short hb = f2bf_rn(v);
            float hf = bf2f(hb);
            unsigned short lb = f2bf_rn(v - hf);
            float lf = bf2f(lb);
            tile[dd][nn_r] = make_ushort2(hb, lb);
            a1 += v * v;
            a2 += lf * lf;
        }
        __syncthreads();
        int kk = t & 63, ng = t >> 6;
        float dimsum = 0.f;
        for (int i2 = 0; i2 < 16; ++i2) {
            int nn = ng + i2 * 4;
            ushort2 hl = tile[kk][nn];
            size_t base = (size_t)(n0 + nn) * 256;
            Ahi[base + dc + kk] = hl.x;
            Alo[base + dc + kk] = hl.y;
            dimsum += bf2f(hl.x) + bf2f(hl.y);
        }
        atomicAdd(&pz[dc + kk], dimsum);
        __syncthreads();
    }
    atomicAdd(&zacc[nn_r], a1);
    atomicAdd(&lacc[nn_r], a2);
    __syncthreads();
    if (t < 64) {
        zsq[n0 + t] = zacc[t];
        sA[n0 + t] = 2.1f * sqrtf(lacc[t]);
        sB[n0 + t] = 2.1f * sqrtf(zacc[t]);
    }
    partialZ[blockIdx.x * 256 + t] = pz[t];
}

// ---------------------------------------------------------------------------
// splitW: w (row-major [256][256]) -> Ws [256][768] = [whi|whi|wlo]
// ---------------------------------------------------------------------------
__global__ void k_splitW(const float* __restrict__ w1, const float* __restrict__ w2,
                         unsigned short* __restrict__ W1s, unsigned short* __restrict__ W2s) {
    int bid = blockIdx.x;
    int row = bid & 255;
    const float* src = (bid >> 8) ? w2 : w1;
    unsigned short* dst = ((bid >> 8) ? W2s : W1s) + (size_t)row * 768;
    int t = threadIdx.x;
    float v = src[row * 256 + t];
    unsigned short hb = f2bf_rn(v);
    unsigned short lb = f2bf_rn(v - bf2f(hb));
    dst[t] = hb;
    dst[256 + t] = hb;
    dst[512 + t] = lb;
}

// ---------------------------------------------------------------------------
// buildE: emb [8192][256] -> E' [8192][768] = [ehi|elo|ehi]
// ---------------------------------------------------------------------------
__global__ void k_buildE(const float* __restrict__ emb, unsigned short* __restrict__ E) {
    int t = threadIdx.x;
    int row = blockIdx.x * 4 + (t >> 6);
    int e4 = (t & 63) * 4;
    float4 v = *(const float4*)&emb[(size_t)row * 256 + e4];
    ushort4 hi, lo;
    hi.x = f2bf_rn(v.x); lo.x = f2bf_rn(v.x - bf2f(hi.x));
    hi.y = f2bf_rn(v.y); lo.y = f2bf_rn(v.y - bf2f(hi.y));
    hi.z = f2bf_rn(v.z); lo.z = f2bf_rn(v.z - bf2f(hi.z));
    hi.w = f2bf_rn(v.w); lo.w = f2bf_rn(v.w - bf2f(hi.w));
    size_t base = (size_t)row * 768;
    *(ushort4*)&E[base + e4] = hi;
    *(ushort4*)&E[base + 256 + e4] = lo;
    *(ushort4*)&E[base + 512 + e4] = hi;
}

// ---------------------------------------------------------------------------
// MLP GEMM on split-bf16 MFMA, 128x128 tiles, r3 2-barrier K-loop (12 kc).
// ---------------------------------------------------------------------------
template <int GELU>
__global__ __launch_bounds__(256) void k_mlp(const unsigned short* __restrict__ A,
                                             const unsigned short* __restrict__ B,
                                             unsigned short* __restrict__ Hs,
                                             float* __restrict__ C_t) {
    __shared__ __align__(16) char smem[32768];
    unsigned short* Asm = (unsigned short*)smem;
    unsigned short* Bsm = (unsigned short*)(smem + 16384);

    int t = threadIdx.x;
    int lane = t & 63;
    int w = t >> 6;
    int wm = w >> 1, wn = w & 1;
    int m0 = blockIdx.y * 128;
    int n0 = blockIdx.x * 128;

    int rA = w * 8 + (lane >> 3);
    int ch_l = lane & 7;
    int ch_g = ch_l ^ (lane >> 3);
    const unsigned short* gA = A + (size_t)(m0 + rA) * 768 + ch_g * 8;
    const unsigned short* gB = B + (size_t)(n0 + rA) * 768 + ch_g * 8;
    unsigned short* lA = &Asm[rA * 64 + ch_l * 8];
    unsigned short* lB = &Bsm[rA * 64 + ch_l * 8];

    f32x4 acc[4][4];
#pragma unroll
    for (int i = 0; i < 4; ++i)
#pragma unroll
        for (int j = 0; j < 4; ++j)
            acc[i][j] = f32x4{0.f, 0.f, 0.f, 0.f};

#pragma unroll
    for (int i = 0; i < 4; ++i) {
        gl2lds16(gA + (size_t)(32 * i) * 768, lA + 32 * i * 64);
        gl2lds16(gB + (size_t)(32 * i) * 768, lB + 32 * i * 64);
    }
    __syncthreads();

    int l15 = lane & 15;
    int quad = lane >> 4;
    int sw = l15 & 7;
    for (int kc = 0; kc < 12; ++kc) {
#pragma unroll
        for (int kk = 0; kk < 2; ++kk) {
            short8 a[4], b[4];
#pragma unroll
            for (int i = 0; i < 4; ++i)
                a[i] = *(const short8*)&Asm[(wm * 64 + i * 16 + l15) * 64 +
                                            (((kk * 4 + quad) ^ sw) * 8)];
#pragma unroll
            for (int j = 0; j < 4; ++j)
                b[j] = *(const short8*)&Bsm[(wn * 64 + j * 16 + l15) * 64 +
                                            (((kk * 4 + quad) ^ sw) * 8)];
#pragma unroll
            for (int i = 0; i < 4; ++i)
#pragma unroll
                for (int j = 0; j < 4; ++j)
                    acc[i][j] = __builtin_amdgcn_mfma_f32_16x16x32_bf16(a[i], b[j], acc[i][j], 0, 0, 0);
        }
        __syncthreads();
        if (kc < 11) {
            int ko = (kc + 1) * 64;
#pragma unroll
            for (int i = 0; i < 4; ++i) {
                gl2lds16(gA + (size_t)(32 * i) * 768 + ko, lA + 32 * i * 64);
                gl2lds16(gB + (size_t)(32 * i) * 768 + ko, lB + 32 * i * 64);
            }
            __syncthreads();
        }
    }

    // epilogue: C/D layout col=lane&15, row=quad*4+reg
#pragma unroll
    for (int i = 0; i < 4; ++i) {
#pragma unroll
        for (int reg = 0; reg < 4; ++reg) {
            int mrow = m0 + wm * 64 + i * 16 + quad * 4 + reg;
#pragma unroll
            for (int j = 0; j < 4; ++j) {
                int ncol = n0 + wn * 64 + j * 16 + l15;
                float h = acc[i][j][reg];
                if (GELU) {
                    float g = 0.5f * h * (1.f + erff(h * 0.70710678118654752f));
                    unsigned short hb = f2bf_rn(g);
                    unsigned short lb = f2bf_rn(g - bf2f(hb));
                    size_t base = (size_t)mrow * 768;
                    Hs[base + ncol] = hb;
                    Hs[base + 256 + ncol] = lb;
                    Hs[base + 512 + ncol] = hb;
                } else {
                    C_t[(size_t)mrow * 8192 + ncol] = h;
                }
            }
        }
    }
}

// ---------------------------------------------------------------------------
// buildB: C_t [256][8192] -> Bhi/Blo [KCB][256]; csq, sC, sCl; per-128-tile
// maxima of sC/sCl; global maxima into accums[3]/[4]; per-dim partial sums.
// ---------------------------------------------------------------------------
__global__ void k_buildB(const float* __restrict__ C_t,
                         unsigned short* __restrict__ Bhi,
                         unsigned short* __restrict__ Blo,
                         float* __restrict__ csq,
                         float* __restrict__ sC, float* __restrict__ sCl,
                         unsigned* __restrict__ tileMaxC, unsigned* __restrict__ tileMaxCl,
                         float* __restrict__ accums, float* __restrict__ partialC) {
    __shared__ ushort2 tile[64][65];
    __shared__ float kacc[64];
    __shared__ float lacc[64];
    __shared__ float pc[256];
    int t = threadIdx.x;
    int k0 = blockIdx.x * 64;
    if (t < 64) { kacc[t] = 0.f; lacc[t] = 0.f; }
    pc[t] = 0.f;
    __syncthreads();
    int nn_r = t & 63, dg = t >> 6;
    float a1 = 0.f, a2 = 0.f;
    for (int dc = 0; dc < 256; dc += 64) {
        for (int r = 0; r < 16; ++r) {
            int dd = r * 4 + dg;
            float v = C_t[(size_t)(dc + dd) * KCB + k0 + nn_r];
            unsigned short hb = f2bf_rn(v);
            float hf = bf2f(hb);
            unsigned short lb = f2bf_rn(v - hf);
            float lf = bf2f(lb);
            tile[dd][nn_r] = make_ushort2(hb, lb);
            a1 += v * v;
            a2 += lf * lf;
        }
        __syncthreads();
        int kk = t & 63, ng = t >> 6;
        float dimsum = 0.f;
        for (int i2 = 0; i2 < 16; ++i2) {
            int nn = ng + i2 * 4;
            ushort2 hl = tile[kk][nn];
            size_t base = (size_t)(k0 + nn) * 256;
            Bhi[base + dc + kk] = hl.x;
            Blo[base + dc + kk] = hl.y;
            dimsum += bf2f(hl.x) + bf2f(hl.y);
        }
        atomicAdd(&pc[dc + kk], dimsum);
        __syncthreads();
    }
    atomicAdd(&kacc[nn_r], a1);
    atomicAdd(&lacc[nn_r], a2);
    __syncthreads();
    if (t < 64) {
        float c2 = kacc[t], l2 = lacc[t];
        float sc = sqrtf(c2), sl = sqrtf(l2);
        csq[k0 + t] = c2;
        sC[k0 + t] = sc;
        sCl[k0 + t] = sl;
        int tl = blockIdx.x >> 1;
        atomicMax(&tileMaxC[tl], __float_as_uint(sc));
        atomicMax(&tileMaxCl[tl], __float_as_uint(sl));
        atomicMax((unsigned*)&accums[3], __float_as_uint(c2));
        atomicMax((unsigned*)&accums[4], __float_as_uint(l2));
    }
    partialC[blockIdx.x * 256 + t] = pc[t];
}

// ---------------------------------------------------------------------------
// Phase-1: d_hi GEMM, BM=256 x BN=256, 512 threads (8 waves), BK=64, 4 kc.
// R1-best structure (137 us measured): 2 x 64 KB LDS dbuf, stage(kc+1)
// issued before compute of kc, one __syncthreads per kc. Launched as TWO
// n-half dispatches (visibility instrumentation: any tail kernel > ~70 us
// now surfaces in rocprof top-5; half 2 also reads half 1's row mins ->
// tighter thresholds). XCD-bijective swizzle per half: 16m x 8n supertile
// per XCD (3 MB L2 working set). Candidate appends are ballot-aggregated:
// one LDS atomic per wave-ballot instead of per element (kills the
// same-address serialization of ~1-3k atomics/block).
// ---------------------------------------------------------------------------
__global__ __launch_bounds__(512, 2) void k_dist_hi(const unsigned short* __restrict__ A,
                                                    const unsigned short* __restrict__ B,
                                                    const float* __restrict__ zsq,
                                                    const float* __restrict__ csq,
                                                    const float* __restrict__ sA,
                                                    const float* __restrict__ sB,
                                                    const unsigned* __restrict__ tileMaxC,
                                                    const unsigned* __restrict__ tileMaxCl,
                                                    unsigned long long* __restrict__ packed,
                                                    float* __restrict__ accums,
                                                    int nhalf,
                                                    unsigned long long* __restrict__ cand) {
    __shared__ __align__(16) char smem[131072];
    // buffer set b (b=0,1) at ushort offset b*32768:
    //   A [256][64] ushort (32 KB) at +0, B [256][64] (32 KB) at +16384
    // epilogue aliases (valid only after the final K-loop barrier):
    float* sbd     = (float*)smem;                   // [2][256]  0..2048
    float* gprev_s = (float*)(smem + 2048);          // [256]
    float* thr     = (float*)(smem + 3072);          // [256]
    unsigned* scnt  = (unsigned*)(smem + 4096);
    unsigned* sbase = (unsigned*)(smem + 4100);
    unsigned long long* scand = (unsigned long long*)(smem + 4112); // [SCAP]

    int t = threadIdx.x;
    int lane = t & 63;
    int w = t >> 6;                 // 0..7
    int wm = w >> 1, wn = w & 1;    // wm 0..3 (64 rows each), wn 0..1 (128 cols each)

    // XCD-bijective swizzle within this n-half: 1024 blocks = 8 XCD chunks
    // of 128; each chunk a 16(m) x 8(n) supertile: 16 A panels (2 MB) +
    // 8 B panels (1 MB) L2-resident.
    unsigned f = blockIdx.x + (blockIdx.y << 6);   // gridDim = (64,16)
    unsigned xcd = f & 7, i5 = f >> 3;             // i5: 0..127
    unsigned mb = (xcd & 3) * 16 + (i5 & 15);      // 0..63
    unsigned nb = (unsigned)nhalf * 16 + (xcd >> 2) * 8 + (i5 >> 4); // 0..31
    int m0 = (int)mb * 256;
    int n0 = (int)nb * 256;

    // staging addresses (LDS-linear dest + source chunk swizzle)
    int rA0 = w * 8 + (lane >> 3);  // 0..63
    int ch_l = lane & 7;
    int ch_g = ch_l ^ (lane >> 3);
    const unsigned short* gA = A + (size_t)(m0 + rA0) * 256 + ch_g * 8;
    const unsigned short* gB = B + (size_t)(n0 + rA0) * 256 + ch_g * 8;
    unsigned short* smemU = (unsigned short*)smem;
    unsigned short* lA = smemU + rA0 * 64 + ch_l * 8;           // within buf0 A
    unsigned short* lB = smemU + 16384 + rA0 * 64 + ch_l * 8;   // within buf0 B

    int l15 = lane & 15;
    int quad = lane >> 4;
    int sw = l15 & 7;

    // hoisted uniform epilogue constants
    float M1 = sqrtf(accums[3]);
    float M2 = sqrtf(accums[4]);
    float msC  = fmaxf(__uint_as_float(tileMaxC[2 * nb]),
                       __uint_as_float(tileMaxC[2 * nb + 1]));
    float msCl = fmaxf(__uint_as_float(tileMaxCl[2 * nb]),
                       __uint_as_float(tileMaxCl[2 * nb + 1]));

    f32x4 acc[4][8];
#pragma unroll
    for (int i = 0; i < 4; ++i)
#pragma unroll
        for (int j = 0; j < 8; ++j)
            acc[i][j] = f32x4{0.f, 0.f, 0.f, 0.f};

    // stage buffer set B_ with K-offset KO (elements): 8 gl2lds per thread
#define STAGE(B_, KO)                                                       \
    {                                                                       \
        int off_ = (B_) * 32768;                                            \
        _Pragma("unroll")                                                   \
        for (int i_ = 0; i_ < 4; ++i_)                                      \
            gl2lds16(gA + (size_t)(64 * i_) * 256 + (KO),                   \
                     lA + off_ + 64 * i_ * 64);                             \
        _Pragma("unroll")                                                   \
        for (int i_ = 0; i_ < 4; ++i_)                                      \
            gl2lds16(gB + (size_t)(64 * i_) * 256 + (KO),                   \
                     lB + off_ + 64 * i_ * 64);                             \
    }

    // prologue: stage kc=0 into buf 0
    STAGE(0, 0)
    __syncthreads();   // kc=0 tile landed

    int cur = 0;
    for (int kc = 0; kc < 4; ++kc) {
        // issue next stage into the other buffer BEFORE compute
        if (kc < 3) STAGE(cur ^ 1, (kc + 1) * 64)
        const unsigned short* Ar = smemU + cur * 32768;
        const unsigned short* Br = Ar + 16384;
#pragma unroll
        for (int kk = 0; kk < 2; ++kk) {
            short8 a[4], b[8];
#pragma unroll
            for (int i = 0; i < 4; ++i)
                a[i] = *(const short8*)&Ar[(wm * 64 + i * 16 + l15) * 64 +
                                            (((kk * 4 + quad) ^ sw) * 8)];
#pragma unroll
            for (int j = 0; j < 8; ++j)
                b[j] = *(const short8*)&Br[(wn * 128 + j * 16 + l15) * 64 +
                                            (((kk * 4 + quad) ^ sw) * 8)];
#pragma unroll
            for (int i = 0; i < 4; ++i)
#pragma unroll
                for (int j = 0; j < 8; ++j)
                    acc[i][j] = __builtin_amdgcn_mfma_f32_16x16x32_bf16(a[i], b[j], acc[i][j], 0, 0, 0);
        }
        __syncthreads();
        cur ^= 1;
    }
#undef STAGE

    // epilogue-only per-lane loads
    float cv[8];
    int cols[8];
#pragma unroll
    for (int j = 0; j < 8; ++j) {
        int cloc = wn * 128 + j * 16 + l15;
        cols[j] = n0 + cloc;
        cv[j] = csq[cols[j]];
    }

    // ---- pass 1: transform in place + value-only per-row min
    if (t == 0) *scnt = 0;
    if (t < 256) {
        const unsigned* hp = (const unsigned*)&packed[m0 + t];
        gprev_s[t] = __uint_as_float(__atomic_load_n(hp + 1, __ATOMIC_RELAXED));
    }
#pragma unroll
    for (int i = 0; i < 4; ++i) {
#pragma unroll
        for (int reg = 0; reg < 4; ++reg) {
            int rloc = wm * 64 + i * 16 + quad * 4 + reg;
            float zs = zsq[m0 + rloc];
            float bd = 3.4e38f;
#pragma unroll
            for (int j = 0; j < 8; ++j) {
                float d = (zs + cv[j]) - 2.0f * acc[i][j][reg];
                acc[i][j][reg] = d;
                bd = fminf(bd, d);
            }
#pragma unroll
            for (int off = 1; off < 16; off <<= 1)
                bd = fminf(bd, __shfl_xor(bd, off, 64));
            if (l15 == 0) sbd[wn * 256 + rloc] = bd;
        }
    }
    __syncthreads();
    // ---- t<256: merge halves, global min (fire-and-forget), row threshold
    if (t < 256) {
        float bd = fminf(sbd[t], sbd[256 + t]);
        atomicMin(&packed[m0 + t], (unsigned long long)__float_as_uint(bd) << 32);
        float g = fminf(bd, gprev_s[t]);
        thr[t] = g + 1e-3f + sA[m0 + t] * (M1 + msC) + sB[m0 + t] * (M2 + msCl);
    }
    __syncthreads();
    // ---- pass 2: 1-compare filter + ballot-aggregated staged appends
    unsigned* cnt = (unsigned*)&accums[2];
#pragma unroll
    for (int i = 0; i < 4; ++i) {
#pragma unroll
        for (int reg = 0; reg < 4; ++reg) {
            int rloc = wm * 64 + i * 16 + quad * 4 + reg;
            float tr = thr[rloc];
            unsigned rbits = (unsigned)((m0 + rloc) << 13);
#pragma unroll
            for (int j = 0; j < 8; ++j) {
                bool p = acc[i][j][reg] <= tr;
                unsigned long long mask = __ballot(p);
                if (mask) {
                    unsigned cw = (unsigned)__popcll(mask);
                    unsigned base;
                    if (lane == 0) base = atomicAdd(scnt, cw);
                    base = __shfl(base, 0, 64);
                    if (p) {
                        unsigned pos = base +
                            (unsigned)__popcll(mask & ((1ull << lane) - 1ull));
                        unsigned long long entry =
                            ((unsigned long long)__float_as_uint(acc[i][j][reg]) << 32) |
                            (rbits | (unsigned)cols[j]);
                        if (pos < SCAP) scand[pos] = entry;
                        else {
                            unsigned gp2 = atomicAdd(cnt, 1u);
                            if (gp2 < CAP) cand[gp2] = entry;
                        }
                    }
                }
            }
        }
    }
    __syncthreads();
    if (t == 0) {
        unsigned m = *scnt;
        if (m > SCAP) m = SCAP;
        *scnt = m;
        *sbase = atomicAdd(cnt, m);
    }
    __syncthreads();
    {
        unsigned m = *scnt, b0 = *sbase;
        for (unsigned u = t; u < m; u += 512)
            if (b0 + u < CAP) cand[b0 + u] = scand[u];
    }
}

// ---------------------------------------------------------------------------
// Phase-2: re-filter vs final row min, exact rescore, lex atomicMin
// ---------------------------------------------------------------------------
__global__ __launch_bounds__(256) void k_rescore(const unsigned long long* __restrict__ cand,
                                                 const unsigned short* __restrict__ Ahi,
                                                 const unsigned short* __restrict__ Alo,
                                                 const unsigned short* __restrict__ Bhi,
                                                 const unsigned short* __restrict__ Blo,
                                                 const float* __restrict__ zsq,
                                                 const float* __restrict__ csq,
                                                 const float* __restrict__ sA,
                                                 const float* __restrict__ sB,
                                                 const float* __restrict__ sC,
                                                 const float* __restrict__ sCl,
                                                 const unsigned long long* __restrict__ packed,
                                                 unsigned long long* __restrict__ packed2,
                                                 const float* __restrict__ accums) {
    unsigned total = *(const unsigned*)&accums[2];
    if (total > CAP) total = CAP;
    float M1 = sqrtf(accums[3]);
    float M2 = sqrtf(accums[4]);
    int lane = threadIdx.x & 63;
    unsigned wv = blockIdx.x * 4 + (threadIdx.x >> 6);
    unsigned nw = gridDim.x * 4;
    for (unsigned e = wv; e < total; e += nw) {
        unsigned long long ent = cand[e];
        float dhi = __uint_as_float((unsigned)(ent >> 32));
        unsigned nk = (unsigned)ent;
        int n = (nk >> 13) & 16383;
        int k = nk & 8191;
        float g = __uint_as_float((unsigned)(packed[n] >> 32));
        float marg = g + 1e-3f + sA[n] * (M1 + sC[k]) + sB[n] * (M2 + sCl[k]);
        if (dhi > marg) continue;
        ushort4 zh = *((const ushort4*)(Ahi + (size_t)n * 256) + lane);
        ushort4 zl = *((const ushort4*)(Alo + (size_t)n * 256) + lane);
        ushort4 ch = *((const ushort4*)(Bhi + (size_t)k * 256) + lane);
        ushort4 cl = *((const ushort4*)(Blo + (size_t)k * 256) + lane);
        float s = (bf2f(zh.x) + bf2f(zl.x)) * (bf2f(ch.x) + bf2f(cl.x))
                + (bf2f(zh.y) + bf2f(zl.y)) * (bf2f(ch.y) + bf2f(cl.y))
                + (bf2f(zh.z) + bf2f(zl.z)) * (bf2f(ch.z) + bf2f(cl.z))
                + (bf2f(zh.w) + bf2f(zl.w)) * (bf2f(ch.w) + bf2f(cl.w));
#pragma unroll
        for (int off = 1; off < 64; off <<= 1)
            s += __shfl_xor(s, off, 64);
        if (lane == 0) {
            float dd = (zsq[n] + csq[k]) - 2.0f * s;
            unsigned long long p =
                ((unsigned long long)__float_as_uint(dd) << 32) | (unsigned)k;
            atomicMin(&packed2[n], p);
        }
    }
}

__global__ void k_unpack(const unsigned long long* __restrict__ packed2,
                         int* __restrict__ idx, int* __restrict__ counts) {
    int n = blockIdx.x * 256 + threadIdx.x;
    unsigned long long p = packed2[n];
    int k = (int)(p & 0xffffffffull);
    idx[n] = k;
    atomicAdd(&counts[k], 1);
}

__global__ void k_zqloss(const float* __restrict__ z, const float* __restrict__ C_t,
                         const int* __restrict__ idx, float* __restrict__ out,
                         float* __restrict__ loss_sum) {
    __shared__ float red[256];
    int bid = blockIdx.x;
    int b = bid >> 8;
    int d = bid & 255;
    int t = threadIdx.x;
    const float* crow = C_t + (size_t)d * KCB;
    const int* ib = idx + b * THW;
    size_t base = ((size_t)(b * DIM + d)) * THW;
    float lsum = 0.f;
    for (int it = 0; it < 32; ++it) {
        int thw = it * 256 + t;
        int id = ib[thw];
        float v = crow[id];
        float zz = z[base + thw];
        out[base + thw] = v;
        float df = v - zz;
        lsum += df * df;
    }
    red[t] = lsum;
    __syncthreads();
    for (int s = 128; s > 0; s >>= 1) {
        if (t < s) red[t] += red[t + s];
        __syncthreads();
    }
    if (t == 0) atomicAdd(loss_sum, red[0]);
}

// ---------------------------------------------------------------------------
// Final scalars: loss, perplexity, closed-form mean_distance
// ---------------------------------------------------------------------------
__global__ void k_scalars(const int* __restrict__ counts,
                          const float* __restrict__ accums,
                          const float* __restrict__ zsq, const float* __restrict__ csq,
                          const float* __restrict__ partialZ,
                          const float* __restrict__ partialC,
                          float* __restrict__ out_tail) {
    __shared__ double redd[256];
    __shared__ float redf[256];
    int t = threadIdx.x;
    double szsq = 0.0, scsq = 0.0;
    for (int n = t; n < NTOK; n += 256) szsq += (double)zsq[n];
    for (int k = t; k < KCB; k += 256) scsq += (double)csq[k];
    float SZ = 0.f, SC = 0.f;
    for (int b2 = 0; b2 < 256; ++b2) SZ += partialZ[b2 * 256 + t];
    for (int b2 = 0; b2 < 128; ++b2) SC += partialC[b2 * 256 + t];
    double total = 8192.0 * szsq + 16384.0 * scsq - 2.0 * (double)SZ * (double)SC;
    redd[t] = total;
    float s = 0.f;
    for (int k = t; k < KCB; k += 256) {
        float e = (float)counts[k] * (1.0f / 16384.0f);
        s += e * logf(e + 1e-10f);
    }
    redf[t] = s;
    __syncthreads();
    for (int st = 128; st > 0; st >>= 1) {
        if (t < st) { redd[t] += redd[t + st]; redf[t] += redf[t + st]; }
        __syncthreads();
    }
    if (t == 0) {
        out_tail[0] = 1.25f * accums[1] / 4194304.0f;
        out_tail[1] = expf(-redf[0]);
        out_tail[2] = (float)(redd[0] / (16384.0 * 8192.0));
    }
}

// ---------------------------------------------------------------------------
extern "C" void kernel_launch(void* const* d_in, const int* in_sizes, int n_in,
                              void* d_out, int out_size, void* d_ws, size_t ws_size,
                              hipStream_t stream) {
    const float* z     = (const float*)d_in[0];   // [2][256][8192]
    const float* emb_w = (const float*)d_in[1];   // [8192][256]
    const float* w1    = (const float*)d_in[2];   // [256][256]
    const float* w2    = (const float*)d_in[3];   // [256][256]
    float* out = (float*)d_out;

    char* w = (char*)d_ws;
    unsigned short* Ahi = (unsigned short*)(w + 0);          //  8,388,608
    unsigned short* Alo = (unsigned short*)(w + 8388608);    //  8,388,608
    unsigned short* Ebf = (unsigned short*)(w + 16777216);   // 12,582,912 (E'; C_t aliases after mlp1)
    unsigned short* Bhi = (unsigned short*)(w + 29360128);   //  4,194,304
    unsigned short* Blo = (unsigned short*)(w + 33554432);   //  4,194,304
    unsigned short* W1s = (unsigned short*)(w + 37748736);   //    393,216
    unsigned short* W2s = (unsigned short*)(w + 38141952);   //    393,216
    float* zsq   = (float*)(w + 38535168);   // 65,536
    float* sA    = (float*)(w + 38666240);   // 65,536
    float* sB    = (float*)(w + 38731776);   // 65,536
    float* csq   = (float*)(w + 38797312);   // 32,768
    float* sC    = (float*)(w + 38862848);   // 32,768
    float* sCl   = (float*)(w + 38895616);   // 32,768
    unsigned long long* packed  = (unsigned long long*)(w + 38928384); // 131,072
    unsigned long long* packed2 = (unsigned long long*)(w + 39059456); // 131,072
    int*   idx    = (int*)(w + 39190528);    // 65,536
    int*   counts = (int*)(w + 39256064);    // 32,768
    float* partialZ = (float*)(w + 39288832); // 262,144
    float* partialC = (float*)(w + 39550976); // 131,072
    unsigned* tileMaxC  = (unsigned*)(w + 39682048); // 256
    unsigned* tileMaxCl = (unsigned*)(w + 39682304); // 256
    float* accums = (float*)(w + 39682560);  // [1]loss [2]cnt [3]csqmax [4]closqmax

    float* C_t = (float*)Ebf;                        // alias: E' dead after mlp1
    unsigned short* Hs = (unsigned short*)d_out;     // Hs then cand share d_out
    unsigned long long* cand = (unsigned long long*)d_out;

    hipMemsetAsync(counts, 0, 32768, stream);
    hipMemsetAsync(tileMaxC, 0, 1024, stream);       // tileMax* + accums
    hipMemsetAsync(packed, 0xFF, 262144, stream);    // packed + packed2

    k_buildA<<<NTOK / 64, 256, 0, stream>>>(z, Ahi, Alo, zsq, sA, sB, partialZ);
    k_splitW<<<512, 256, 0, stream>>>(w1, w2, W1s, W2s);
    k_buildE<<<KCB / 4, 256, 0, stream>>>(emb_w, Ebf);

    // MLP: Hs[k][768] = split(gelu(E' x W1s^T))  (codes on the M side)
    k_mlp<1><<<dim3(2, KCB / 128), 256, 0, stream>>>(Ebf, W1s, Hs, nullptr);
    // C_t[d][8192] = W2s x Hs^T
    k_mlp<0><<<dim3(KCB / 128, 2), 256, 0, stream>>>(W2s, Hs, nullptr, C_t);

    k_buildB<<<KCB / 64, 256, 0, stream>>>(C_t, Bhi, Blo, csq, sC, sCl,
                                           tileMaxC, tileMaxCl, accums, partialC);

    // Phase-1: d_hi GEMM (256x256 tiles, R1 structure), two n-half dispatches
    k_dist_hi<<<dim3(64, 16), 512, 0, stream>>>(
        Ahi, Bhi, zsq, csq, sA, sB, tileMaxC, tileMaxCl, packed, accums, 0, cand);
    k_dist_hi<<<dim3(64, 16), 512, 0, stream>>>(
        Ahi, Bhi, zsq, csq, sA, sB, tileMaxC, tileMaxCl, packed, accums, 1, cand);

    // Phase-2: exact rescore of survivors
    k_rescore<<<1024, 256, 0, stream>>>(cand, Ahi, Alo, Bhi, Blo, zsq, csq,
                                        sA, sB, sC, sCl, packed, packed2, accums);

    k_unpack<<<NTOK / 256, 256, 0, stream>>>(packed2, idx, counts);
    k_zqloss<<<BATCH * DIM, 256, 0, stream>>>(z, C_t, idx, out, accums + 1);
    k_scalars<<<1, 256, 0, stream>>>(counts, accums, zsq, csq, partialZ, partialC, out + OUTQ);
}

// Round 7
// 411.405 us; speedup vs baseline: 1.0791x; 1.0791x over previous
//
#include <hip/hip_runtime.h>
#include <math.h>

// Problem constants (fixed by setup_inputs)
#define BATCH 2
#define DIM   256
#define THW   8192            // T*H*W = 8*32*32
#define NTOK  16384           // BATCH*THW
#define KCB   8192            // codebook size
#define OUTQ  4194304         // BATCH*DIM*THW
#define CAP   2000000         // candidate buffer entries (16 MB in d_out)
#define SCAP  5600            // per-block LDS candidate staging capacity

typedef short short8 __attribute__((ext_vector_type(8)));
typedef float f32x4 __attribute__((ext_vector_type(4)));

__device__ __forceinline__ unsigned short f2bf_rn(float v) {
    unsigned u = __float_as_uint(v);
    unsigned r = u + 0x7FFFu + ((u >> 16) & 1u);
    return (unsigned short)(r >> 16);
}
__device__ __forceinline__ float bf2f(unsigned short b) {
    return __uint_as_float((unsigned)b << 16);
}
__device__ __forceinline__ void gl2lds16(const unsigned short* g, unsigned short* l) {
    __builtin_amdgcn_global_load_lds(
        (const __attribute__((address_space(1))) void*)g,
        (__attribute__((address_space(3))) void*)l, 16, 0, 0);
}

// ---------------------------------------------------------------------------
// splitW: w (row-major [256][256]) -> Ws [256][768] = [whi|whi|wlo].
// Runs FIRST; also folds in all the buffer zeroing that used to be
// hipMemsetAsync (counts, tileMax*, accums, partialZ/C pre-reduce arrays).
// ---------------------------------------------------------------------------
__global__ void k_splitW(const float* __restrict__ w1, const float* __restrict__ w2,
                         unsigned short* __restrict__ W1s, unsigned short* __restrict__ W2s,
                         int* __restrict__ counts,
                         unsigned* __restrict__ tileMaxC, unsigned* __restrict__ tileMaxCl,
                         float* __restrict__ accums,
                         float* __restrict__ partialZ, float* __restrict__ partialC) {
    int bid = blockIdx.x;
    int t = threadIdx.x;
    // housekeeping inits (replace the 3 hipMemsetAsync calls)
    if (bid < 32) {
        counts[bid * 256 + t] = 0;
    } else if (bid == 32) {
        if (t < 64) { tileMaxC[t] = 0u; tileMaxCl[t] = 0u; }
        if (t >= 64 && t < 72) accums[t - 64] = 0.f;
    } else if (bid == 33) {
        partialZ[t] = 0.f;
    } else if (bid == 34) {
        partialC[t] = 0.f;
    }
    int row = bid & 255;
    const float* src = (bid >> 8) ? w2 : w1;
    unsigned short* dst = ((bid >> 8) ? W2s : W1s) + (size_t)row * 768;
    float v = src[row * 256 + t];
    unsigned short hb = f2bf_rn(v);
    unsigned short lb = f2bf_rn(v - bf2f(hb));
    dst[t] = hb;
    dst[256 + t] = hb;
    dst[512 + t] = lb;
}

// ---------------------------------------------------------------------------
// buildA: z -> Ahi/Alo [NTOK][256]; zsq, sA=2.1*sqrt(zlosq), sB=2.1*sqrt(zsq);
// per-dim sums of z atomically into partialZ[256]; also inits packed/packed2
// rows to ~0 (replaces the 256 KB memset).
// ---------------------------------------------------------------------------
__global__ void k_buildA(const float* __restrict__ z,
                         unsigned short* __restrict__ Ahi,
                         unsigned short* __restrict__ Alo,
                         float* __restrict__ zsq,
                         float* __restrict__ sA, float* __restrict__ sB,
                         float* __restrict__ partialZ,
                         unsigned long long* __restrict__ packed,
                         unsigned long long* __restrict__ packed2) {
    __shared__ ushort2 tile[64][65];
    __shared__ float zacc[64];
    __shared__ float lacc[64];
    __shared__ float pz[256];
    int t = threadIdx.x;
    int n0 = blockIdx.x * 64;
    int b = n0 >> 13;
    int thw0 = n0 & 8191;
    if (t < 64) {
        zacc[t] = 0.f; lacc[t] = 0.f;
        packed[n0 + t] = ~0ull;
        packed2[n0 + t] = ~0ull;
    }
    pz[t] = 0.f;
    __syncthreads();
    int nn_r = t & 63, dg = t >> 6;
    float a1 = 0.f, a2 = 0.f;
    for (int dc = 0; dc < 256; dc += 64) {
        for (int r = 0; r < 16; ++r) {
            int dd = r * 4 + dg;
            float v = z[((size_t)(b * 256 + dc + dd)) * 8192 + thw0 + nn_r];
            unsigned short hb = f2bf_rn(v);
            float hf = bf2f(hb);
            unsigned short lb = f2bf_rn(v - hf);
            float lf = bf2f(lb);
            tile[dd][nn_r] = make_ushort2(hb, lb);
            a1 += v * v;
            a2 += lf * lf;
        }
        __syncthreads();
        int kk = t & 63, ng = t >> 6;
        float dimsum = 0.f;
        for (int i2 = 0; i2 < 16; ++i2) {
            int nn = ng + i2 * 4;
            ushort2 hl = tile[kk][nn];
            size_t base = (size_t)(n0 + nn) * 256;
            Ahi[base + dc + kk] = hl.x;
            Alo[base + dc + kk] = hl.y;
            dimsum += bf2f(hl.x) + bf2f(hl.y);
        }
        atomicAdd(&pz[dc + kk], dimsum);
        __syncthreads();
    }
    atomicAdd(&zacc[nn_r], a1);
    atomicAdd(&lacc[nn_r], a2);
    __syncthreads();
    if (t < 64) {
        zsq[n0 + t] = zacc[t];
        sA[n0 + t] = 2.1f * sqrtf(lacc[t]);
        sB[n0 + t] = 2.1f * sqrtf(zacc[t]);
    }
    atomicAdd(&partialZ[t], pz[t]);
}

// ---------------------------------------------------------------------------
// buildE: emb [8192][256] -> E' [8192][768] = [ehi|elo|ehi]
// ---------------------------------------------------------------------------
__global__ void k_buildE(const float* __restrict__ emb, unsigned short* __restrict__ E) {
    int t = threadIdx.x;
    int row = blockIdx.x * 4 + (t >> 6);
    int e4 = (t & 63) * 4;
    float4 v = *(const float4*)&emb[(size_t)row * 256 + e4];
    ushort4 hi, lo;
    hi.x = f2bf_rn(v.x); lo.x = f2bf_rn(v.x - bf2f(hi.x));
    hi.y = f2bf_rn(v.y); lo.y = f2bf_rn(v.y - bf2f(hi.y));
    hi.z = f2bf_rn(v.z); lo.z = f2bf_rn(v.z - bf2f(hi.z));
    hi.w = f2bf_rn(v.w); lo.w = f2bf_rn(v.w - bf2f(hi.w));
    size_t base = (size_t)row * 768;
    *(ushort4*)&E[base + e4] = hi;
    *(ushort4*)&E[base + 256 + e4] = lo;
    *(ushort4*)&E[base + 512 + e4] = hi;
}

// ---------------------------------------------------------------------------
// MLP GEMM on split-bf16 MFMA, 128x128 tiles, r3 2-barrier K-loop (12 kc).
// ---------------------------------------------------------------------------
template <int GELU>
__global__ __launch_bounds__(256) void k_mlp(const unsigned short* __restrict__ A,
                                             const unsigned short* __restrict__ B,
                                             unsigned short* __restrict__ Hs,
                                             float* __restrict__ C_t) {
    __shared__ __align__(16) char smem[32768];
    unsigned short* Asm = (unsigned short*)smem;
    unsigned short* Bsm = (unsigned short*)(smem + 16384);

    int t = threadIdx.x;
    int lane = t & 63;
    int w = t >> 6;
    int wm = w >> 1, wn = w & 1;
    int m0 = blockIdx.y * 128;
    int n0 = blockIdx.x * 128;

    int rA = w * 8 + (lane >> 3);
    int ch_l = lane & 7;
    int ch_g = ch_l ^ (lane >> 3);
    const unsigned short* gA = A + (size_t)(m0 + rA) * 768 + ch_g * 8;
    const unsigned short* gB = B + (size_t)(n0 + rA) * 768 + ch_g * 8;
    unsigned short* lA = &Asm[rA * 64 + ch_l * 8];
    unsigned short* lB = &Bsm[rA * 64 + ch_l * 8];

    f32x4 acc[4][4];
#pragma unroll
    for (int i = 0; i < 4; ++i)
#pragma unroll
        for (int j = 0; j < 4; ++j)
            acc[i][j] = f32x4{0.f, 0.f, 0.f, 0.f};

#pragma unroll
    for (int i = 0; i < 4; ++i) {
        gl2lds16(gA + (size_t)(32 * i) * 768, lA + 32 * i * 64);
        gl2lds16(gB + (size_t)(32 * i) * 768, lB + 32 * i * 64);
    }
    __syncthreads();

    int l15 = lane & 15;
    int quad = lane >> 4;
    int sw = l15 & 7;
    for (int kc = 0; kc < 12; ++kc) {
#pragma unroll
        for (int kk = 0; kk < 2; ++kk) {
            short8 a[4], b[4];
#pragma unroll
            for (int i = 0; i < 4; ++i)
                a[i] = *(const short8*)&Asm[(wm * 64 + i * 16 + l15) * 64 +
                                            (((kk * 4 + quad) ^ sw) * 8)];
#pragma unroll
            for (int j = 0; j < 4; ++j)
                b[j] = *(const short8*)&Bsm[(wn * 64 + j * 16 + l15) * 64 +
                                            (((kk * 4 + quad) ^ sw) * 8)];
#pragma unroll
            for (int i = 0; i < 4; ++i)
#pragma unroll
                for (int j = 0; j < 4; ++j)
                    acc[i][j] = __builtin_amdgcn_mfma_f32_16x16x32_bf16(a[i], b[j], acc[i][j], 0, 0, 0);
        }
        __syncthreads();
        if (kc < 11) {
            int ko = (kc + 1) * 64;
#pragma unroll
            for (int i = 0; i < 4; ++i) {
                gl2lds16(gA + (size_t)(32 * i) * 768 + ko, lA + 32 * i * 64);
                gl2lds16(gB + (size_t)(32 * i) * 768 + ko, lB + 32 * i * 64);
            }
            __syncthreads();
        }
    }

    // epilogue: C/D layout col=lane&15, row=quad*4+reg
#pragma unroll
    for (int i = 0; i < 4; ++i) {
#pragma unroll
        for (int reg = 0; reg < 4; ++reg) {
            int mrow = m0 + wm * 64 + i * 16 + quad * 4 + reg;
#pragma unroll
            for (int j = 0; j < 4; ++j) {
                int ncol = n0 + wn * 64 + j * 16 + l15;
                float h = acc[i][j][reg];
                if (GELU) {
                    float g = 0.5f * h * (1.f + erff(h * 0.70710678118654752f));
                    unsigned short hb = f2bf_rn(g);
                    unsigned short lb = f2bf_rn(g - bf2f(hb));
                    size_t base = (size_t)mrow * 768;
                    Hs[base + ncol] = hb;
                    Hs[base + 256 + ncol] = lb;
                    Hs[base + 512 + ncol] = hb;
                } else {
                    C_t[(size_t)mrow * 8192 + ncol] = h;
                }
            }
        }
    }
}

// ---------------------------------------------------------------------------
// buildB: C_t [256][8192] -> Bhi/Blo [KCB][256]; csq, sC, sCl; per-128-tile
// maxima of sC/sCl; global maxima into accums[3]/[4]; per-dim sums atomically
// into partialC[256].
// ---------------------------------------------------------------------------
__global__ void k_buildB(const float* __restrict__ C_t,
                         unsigned short* __restrict__ Bhi,
                         unsigned short* __restrict__ Blo,
                         float* __restrict__ csq,
                         float* __restrict__ sC, float* __restrict__ sCl,
                         unsigned* __restrict__ tileMaxC, unsigned* __restrict__ tileMaxCl,
                         float* __restrict__ accums, float* __restrict__ partialC) {
    __shared__ ushort2 tile[64][65];
    __shared__ float kacc[64];
    __shared__ float lacc[64];
    __shared__ float pc[256];
    int t = threadIdx.x;
    int k0 = blockIdx.x * 64;
    if (t < 64) { kacc[t] = 0.f; lacc[t] = 0.f; }
    pc[t] = 0.f;
    __syncthreads();
    int nn_r = t & 63, dg = t >> 6;
    float a1 = 0.f, a2 = 0.f;
    for (int dc = 0; dc < 256; dc += 64) {
        for (int r = 0; r < 16; ++r) {
            int dd = r * 4 + dg;
            float v = C_t[(size_t)(dc + dd) * KCB + k0 + nn_r];
            unsigned short hb = f2bf_rn(v);
            float hf = bf2f(hb);
            unsigned short lb = f2bf_rn(v - hf);
            float lf = bf2f(lb);
            tile[dd][nn_r] = make_ushort2(hb, lb);
            a1 += v * v;
            a2 += lf * lf;
        }
        __syncthreads();
        int kk = t & 63, ng = t >> 6;
        float dimsum = 0.f;
        for (int i2 = 0; i2 < 16; ++i2) {
            int nn = ng + i2 * 4;
            ushort2 hl = tile[kk][nn];
            size_t base = (size_t)(k0 + nn) * 256;
            Bhi[base + dc + kk] = hl.x;
            Blo[base + dc + kk] = hl.y;
            dimsum += bf2f(hl.x) + bf2f(hl.y);
        }
        atomicAdd(&pc[dc + kk], dimsum);
        __syncthreads();
    }
    atomicAdd(&kacc[nn_r], a1);
    atomicAdd(&lacc[nn_r], a2);
    __syncthreads();
    if (t < 64) {
        float c2 = kacc[t], l2 = lacc[t];
        float sc = sqrtf(c2), sl = sqrtf(l2);
        csq[k0 + t] = c2;
        sC[k0 + t] = sc;
        sCl[k0 + t] = sl;
        int tl = blockIdx.x >> 1;
        atomicMax(&tileMaxC[tl], __float_as_uint(sc));
        atomicMax(&tileMaxCl[tl], __float_as_uint(sl));
        atomicMax((unsigned*)&accums[3], __float_as_uint(c2));
        atomicMax((unsigned*)&accums[4], __float_as_uint(l2));
    }
    atomicAdd(&partialC[t], pc[t]);
}

// ---------------------------------------------------------------------------
// Phase-1: d_hi GEMM, BM=256 x BN=256, 512 threads (8 waves), BK=64, 4 kc.
// R1-verbatim structure (137 us measured): 2 x 64 KB LDS dbuf, stage(kc+1)
// issued BEFORE the compute of kc, one __syncthreads per kc. Single 2048-
// block dispatch: the serialized block-scheduling waves are what give most
// blocks a populated packed[] -> tight thresholds (the R6 split broke this
// and candidate writes exploded 8x).
// Value-only row-min; slim 2-pass epilogue + LDS-staged candidate appends.
// ---------------------------------------------------------------------------
__global__ __launch_bounds__(512, 2) void k_dist_hi(const unsigned short* __restrict__ A,
                                                    const unsigned short* __restrict__ B,
                                                    const float* __restrict__ zsq,
                                                    const float* __restrict__ csq,
                                                    const float* __restrict__ sA,
                                                    const float* __restrict__ sB,
                                                    const unsigned* __restrict__ tileMaxC,
                                                    const unsigned* __restrict__ tileMaxCl,
                                                    unsigned long long* __restrict__ packed,
                                                    float* __restrict__ accums,
                                                    unsigned long long* __restrict__ cand) {
    __shared__ __align__(16) char smem[131072];
    // buffer set b (b=0,1) at ushort offset b*32768:
    //   A [256][64] ushort (32 KB) at +0, B [256][64] (32 KB) at +16384
    // epilogue aliases (valid only after the final K-loop barrier):
    float* sbd     = (float*)smem;                   // [2][256]  0..2048
    float* gprev_s = (float*)(smem + 2048);          // [256]
    float* thr     = (float*)(smem + 3072);          // [256]
    unsigned* scnt  = (unsigned*)(smem + 4096);
    unsigned* sbase = (unsigned*)(smem + 4100);
    unsigned long long* scand = (unsigned long long*)(smem + 4112); // [SCAP]

    int t = threadIdx.x;
    int lane = t & 63;
    int w = t >> 6;                 // 0..7
    int wm = w >> 1, wn = w & 1;    // wm 0..3 (64 rows each), wn 0..1 (128 cols each)
    int m0 = blockIdx.x * 256;
    int n0 = blockIdx.y * 256;

    // staging addresses (LDS-linear dest + source chunk swizzle)
    int rA0 = w * 8 + (lane >> 3);  // 0..63
    int ch_l = lane & 7;
    int ch_g = ch_l ^ (lane >> 3);
    const unsigned short* gA = A + (size_t)(m0 + rA0) * 256 + ch_g * 8;
    const unsigned short* gB = B + (size_t)(n0 + rA0) * 256 + ch_g * 8;
    unsigned short* smemU = (unsigned short*)smem;
    unsigned short* lA = smemU + rA0 * 64 + ch_l * 8;           // within buf0 A
    unsigned short* lB = smemU + 16384 + rA0 * 64 + ch_l * 8;   // within buf0 B

    int l15 = lane & 15;
    int quad = lane >> 4;
    int sw = l15 & 7;

    // hoisted uniform epilogue constants
    float M1 = sqrtf(accums[3]);
    float M2 = sqrtf(accums[4]);
    float msC  = fmaxf(__uint_as_float(tileMaxC[2 * blockIdx.y]),
                       __uint_as_float(tileMaxC[2 * blockIdx.y + 1]));
    float msCl = fmaxf(__uint_as_float(tileMaxCl[2 * blockIdx.y]),
                       __uint_as_float(tileMaxCl[2 * blockIdx.y + 1]));
    float cv[8];
    int cols[8];
#pragma unroll
    for (int j = 0; j < 8; ++j) {
        int cloc = wn * 128 + j * 16 + l15;
        cols[j] = n0 + cloc;
        cv[j] = csq[cols[j]];
    }

    f32x4 acc[4][8];
#pragma unroll
    for (int i = 0; i < 4; ++i)
#pragma unroll
        for (int j = 0; j < 8; ++j)
            acc[i][j] = f32x4{0.f, 0.f, 0.f, 0.f};

    // stage buffer set B_ with K-offset KO (elements): 8 gl2lds per thread
#define STAGE(B_, KO)                                                       \
    {                                                                       \
        int off_ = (B_) * 32768;                                            \
        _Pragma("unroll")                                                   \
        for (int i_ = 0; i_ < 4; ++i_)                                      \
            gl2lds16(gA + (size_t)(64 * i_) * 256 + (KO),                   \
                     lA + off_ + 64 * i_ * 64);                             \
        _Pragma("unroll")                                                   \
        for (int i_ = 0; i_ < 4; ++i_)                                      \
            gl2lds16(gB + (size_t)(64 * i_) * 256 + (KO),                   \
                     lB + off_ + 64 * i_ * 64);                             \
    }

    // prologue: stage kc=0 into buf 0
    STAGE(0, 0)
    __syncthreads();   // kc=0 tile landed

    int cur = 0;
    for (int kc = 0; kc < 4; ++kc) {
        // issue next stage into the other buffer BEFORE compute
        if (kc < 3) STAGE(cur ^ 1, (kc + 1) * 64)
        const unsigned short* Ar = smemU + cur * 32768;
        const unsigned short* Br = Ar + 16384;
#pragma unroll
        for (int kk = 0; kk < 2; ++kk) {
            short8 a[4], b[8];
#pragma unroll
            for (int i = 0; i < 4; ++i)
                a[i] = *(const short8*)&Ar[(wm * 64 + i * 16 + l15) * 64 +
                                            (((kk * 4 + quad) ^ sw) * 8)];
#pragma unroll
            for (int j = 0; j < 8; ++j)
                b[j] = *(const short8*)&Br[(wn * 128 + j * 16 + l15) * 64 +
                                            (((kk * 4 + quad) ^ sw) * 8)];
#pragma unroll
            for (int i = 0; i < 4; ++i)
#pragma unroll
                for (int j = 0; j < 8; ++j)
                    acc[i][j] = __builtin_amdgcn_mfma_f32_16x16x32_bf16(a[i], b[j], acc[i][j], 0, 0, 0);
        }
        __syncthreads();
        cur ^= 1;
    }
#undef STAGE

    // ---- pass 1: transform in place + value-only per-row min
    if (t == 0) *scnt = 0;
    if (t < 256) {
        const unsigned* hp = (const unsigned*)&packed[m0 + t];
        gprev_s[t] = __uint_as_float(__atomic_load_n(hp + 1, __ATOMIC_RELAXED));
    }
#pragma unroll
    for (int i = 0; i < 4; ++i) {
#pragma unroll
        for (int reg = 0; reg < 4; ++reg) {
            int rloc = wm * 64 + i * 16 + quad * 4 + reg;
            float zs = zsq[m0 + rloc];
            float bd = 3.4e38f;
#pragma unroll
            for (int j = 0; j < 8; ++j) {
                float d = (zs + cv[j]) - 2.0f * acc[i][j][reg];
                acc[i][j][reg] = d;
                bd = fminf(bd, d);
            }
#pragma unroll
            for (int off = 1; off < 16; off <<= 1)
                bd = fminf(bd, __shfl_xor(bd, off, 64));
            if (l15 == 0) sbd[wn * 256 + rloc] = bd;
        }
    }
    __syncthreads();
    // ---- t<256: merge halves, global min (fire-and-forget), row threshold
    if (t < 256) {
        float bd = fminf(sbd[t], sbd[256 + t]);
        atomicMin(&packed[m0 + t], (unsigned long long)__float_as_uint(bd) << 32);
        float g = fminf(bd, gprev_s[t]);
        thr[t] = g + 1e-3f + sA[m0 + t] * (M1 + msC) + sB[m0 + t] * (M2 + msCl);
    }
    __syncthreads();
    // ---- pass 2: 1-compare filter + staged appends
    unsigned* cnt = (unsigned*)&accums[2];
#pragma unroll
    for (int i = 0; i < 4; ++i) {
#pragma unroll
        for (int reg = 0; reg < 4; ++reg) {
            int rloc = wm * 64 + i * 16 + quad * 4 + reg;
            float tr = thr[rloc];
            bool p[8];
            bool any = false;
#pragma unroll
            for (int j = 0; j < 8; ++j) {
                p[j] = acc[i][j][reg] <= tr;
                any |= p[j];
            }
            if (__ballot(any)) {
                unsigned rbits = (unsigned)((m0 + rloc) << 13);
#pragma unroll
                for (int j = 0; j < 8; ++j) {
                    if (p[j]) {
                        unsigned long long entry =
                            ((unsigned long long)__float_as_uint(acc[i][j][reg]) << 32) |
                            (rbits | (unsigned)cols[j]);
                        unsigned pos = atomicAdd(scnt, 1u);
                        if (pos < SCAP) scand[pos] = entry;
                        else {
                            unsigned gp2 = atomicAdd(cnt, 1u);
                            if (gp2 < CAP) cand[gp2] = entry;
                        }
                    }
                }
            }
        }
    }
    __syncthreads();
    if (t == 0) {
        unsigned m = *scnt;
        if (m > SCAP) m = SCAP;
        *scnt = m;
        *sbase = atomicAdd(cnt, m);
    }
    __syncthreads();
    {
        unsigned m = *scnt, b0 = *sbase;
        for (unsigned u = t; u < m; u += 512)
            if (b0 + u < CAP) cand[b0 + u] = scand[u];
    }
}

// ---------------------------------------------------------------------------
// Phase-2: re-filter vs final row min, exact rescore, lex atomicMin
// ---------------------------------------------------------------------------
__global__ __launch_bounds__(256) void k_rescore(const unsigned long long* __restrict__ cand,
                                                 const unsigned short* __restrict__ Ahi,
                                                 const unsigned short* __restrict__ Alo,
                                                 const unsigned short* __restrict__ Bhi,
                                                 const unsigned short* __restrict__ Blo,
                                                 const float* __restrict__ zsq,
                                                 const float* __restrict__ csq,
                                                 const float* __restrict__ sA,
                                                 const float* __restrict__ sB,
                                                 const float* __restrict__ sC,
                                                 const float* __restrict__ sCl,
                                                 const unsigned long long* __restrict__ packed,
                                                 unsigned long long* __restrict__ packed2,
                                                 const float* __restrict__ accums) {
    unsigned total = *(const unsigned*)&accums[2];
    if (total > CAP) total = CAP;
    float M1 = sqrtf(accums[3]);
    float M2 = sqrtf(accums[4]);
    int lane = threadIdx.x & 63;
    unsigned wv = blockIdx.x * 4 + (threadIdx.x >> 6);
    unsigned nw = gridDim.x * 4;
    for (unsigned e = wv; e < total; e += nw) {
        unsigned long long ent = cand[e];
        float dhi = __uint_as_float((unsigned)(ent >> 32));
        unsigned nk = (unsigned)ent;
        int n = (nk >> 13) & 16383;
        int k = nk & 8191;
        float g = __uint_as_float((unsigned)(packed[n] >> 32));
        float marg = g + 1e-3f + sA[n] * (M1 + sC[k]) + sB[n] * (M2 + sCl[k]);
        if (dhi > marg) continue;
        ushort4 zh = *((const ushort4*)(Ahi + (size_t)n * 256) + lane);
        ushort4 zl = *((const ushort4*)(Alo + (size_t)n * 256) + lane);
        ushort4 ch = *((const ushort4*)(Bhi + (size_t)k * 256) + lane);
        ushort4 cl = *((const ushort4*)(Blo + (size_t)k * 256) + lane);
        float s = (bf2f(zh.x) + bf2f(zl.x)) * (bf2f(ch.x) + bf2f(cl.x))
                + (bf2f(zh.y) + bf2f(zl.y)) * (bf2f(ch.y) + bf2f(cl.y))
                + (bf2f(zh.z) + bf2f(zl.z)) * (bf2f(ch.z) + bf2f(cl.z))
                + (bf2f(zh.w) + bf2f(zl.w)) * (bf2f(ch.w) + bf2f(cl.w));
#pragma unroll
        for (int off = 1; off < 64; off <<= 1)
            s += __shfl_xor(s, off, 64);
        if (lane == 0) {
            float dd = (zsq[n] + csq[k]) - 2.0f * s;
            unsigned long long p =
                ((unsigned long long)__float_as_uint(dd) << 32) | (unsigned)k;
            atomicMin(&packed2[n], p);
        }
    }
}

// ---------------------------------------------------------------------------
// zqloss (+fused unpack): reads packed2 directly for code indices, gathers
// codebook rows, writes out, accumulates VQ loss; d==0 blocks also build the
// counts histogram (replaces k_unpack).
// ---------------------------------------------------------------------------
__global__ void k_zqloss(const float* __restrict__ z, const float* __restrict__ C_t,
                         const unsigned long long* __restrict__ packed2,
                         float* __restrict__ out, float* __restrict__ loss_sum,
                         int* __restrict__ counts) {
    __shared__ float red[256];
    int bid = blockIdx.x;
    int b = bid >> 8;
    int d = bid & 255;
    int t = threadIdx.x;
    const float* crow = C_t + (size_t)d * KCB;
    const unsigned long long* pb = packed2 + (size_t)b * THW;
    size_t base = ((size_t)(b * DIM + d)) * THW;
    float lsum = 0.f;
    for (int it = 0; it < 8; ++it) {
        int thw = it * 1024 + t * 4;
        ulonglong2 p01 = *(const ulonglong2*)&pb[thw];
        ulonglong2 p23 = *(const ulonglong2*)&pb[thw + 2];
        int i0 = (int)(unsigned)p01.x & 8191;
        int i1 = (int)(unsigned)p01.y & 8191;
        int i2 = (int)(unsigned)p23.x & 8191;
        int i3 = (int)(unsigned)p23.y & 8191;
        float4 zz = *(const float4*)&z[base + thw];
        float4 v;
        v.x = crow[i0]; v.y = crow[i1]; v.z = crow[i2]; v.w = crow[i3];
        *(float4*)&out[base + thw] = v;
        float d0 = v.x - zz.x, d1 = v.y - zz.y, d2 = v.z - zz.z, d3 = v.w - zz.w;
        lsum += d0 * d0 + d1 * d1 + d2 * d2 + d3 * d3;
        if (d == 0) {
            atomicAdd(&counts[i0], 1);
            atomicAdd(&counts[i1], 1);
            atomicAdd(&counts[i2], 1);
            atomicAdd(&counts[i3], 1);
        }
    }
    red[t] = lsum;
    __syncthreads();
    for (int s = 128; s > 0; s >>= 1) {
        if (t < s) red[t] += red[t + s];
        __syncthreads();
    }
    if (t == 0) atomicAdd(loss_sum, red[0]);
}

// ---------------------------------------------------------------------------
// Final scalars: loss, perplexity, closed-form mean_distance.
// partialZ/partialC are already fully reduced [256] arrays.
// ---------------------------------------------------------------------------
__global__ void k_scalars(const int* __restrict__ counts,
                          const float* __restrict__ accums,
                          const float* __restrict__ zsq, const float* __restrict__ csq,
                          const float* __restrict__ partialZ,
                          const float* __restrict__ partialC,
                          float* __restrict__ out_tail) {
    __shared__ double redd[256];
    __shared__ float redf[256];
    int t = threadIdx.x;
    double szsq = 0.0, scsq = 0.0;
    for (int n = t; n < NTOK; n += 256) szsq += (double)zsq[n];
    for (int k = t; k < KCB; k += 256) scsq += (double)csq[k];
    float SZ = partialZ[t];
    float SC = partialC[t];
    double total = 8192.0 * szsq + 16384.0 * scsq - 2.0 * (double)SZ * (double)SC;
    redd[t] = total;
    float s = 0.f;
    for (int k = t; k < KCB; k += 256) {
        float e = (float)counts[k] * (1.0f / 16384.0f);
        s += e * logf(e + 1e-10f);
    }
    redf[t] = s;
    __syncthreads();
    for (int st = 128; st > 0; st >>= 1) {
        if (t < st) { redd[t] += redd[t + st]; redf[t] += redf[t + st]; }
        __syncthreads();
    }
    if (t == 0) {
        out_tail[0] = 1.25f * accums[1] / 4194304.0f;
        out_tail[1] = expf(-redf[0]);
        out_tail[2] = (float)(redd[0] / (16384.0 * 8192.0));
    }
}

// ---------------------------------------------------------------------------
extern "C" void kernel_launch(void* const* d_in, const int* in_sizes, int n_in,
                              void* d_out, int out_size, void* d_ws, size_t ws_size,
                              hipStream_t stream) {
    const float* z     = (const float*)d_in[0];   // [2][256][8192]
    const float* emb_w = (const float*)d_in[1];   // [8192][256]
    const float* w1    = (const float*)d_in[2];   // [256][256]
    const float* w2    = (const float*)d_in[3];   // [256][256]
    float* out = (float*)d_out;

    char* w = (char*)d_ws;
    unsigned short* Ahi = (unsigned short*)(w + 0);          //  8,388,608
    unsigned short* Alo = (unsigned short*)(w + 8388608);    //  8,388,608
    unsigned short* Ebf = (unsigned short*)(w + 16777216);   // 12,582,912 (E'; C_t aliases after mlp1)
    unsigned short* Bhi = (unsigned short*)(w + 29360128);   //  4,194,304
    unsigned short* Blo = (unsigned short*)(w + 33554432);   //  4,194,304
    unsigned short* W1s = (unsigned short*)(w + 37748736);   //    393,216
    unsigned short* W2s = (unsigned short*)(w + 38141952);   //    393,216
    float* zsq   = (float*)(w + 38535168);   // 65,536
    float* sA    = (float*)(w + 38666240);   // 65,536
    float* sB    = (float*)(w + 38731776);   // 65,536
    float* csq   = (float*)(w + 38797312);   // 32,768
    float* sC    = (float*)(w + 38862848);   // 32,768
    float* sCl   = (float*)(w + 38895616);   // 32,768
    unsigned long long* packed  = (unsigned long long*)(w + 38928384); // 131,072
    unsigned long long* packed2 = (unsigned long long*)(w + 39059456); // 131,072
    int*   counts = (int*)(w + 39256064);    // 32,768
    float* partialZ = (float*)(w + 39288832); // [256] pre-reduced
    float* partialC = (float*)(w + 39550976); // [256] pre-reduced
    unsigned* tileMaxC  = (unsigned*)(w + 39682048); // 256
    unsigned* tileMaxCl = (unsigned*)(w + 39682304); // 256
    float* accums = (float*)(w + 39682560);  // [1]loss [2]cnt [3]csqmax [4]closqmax

    float* C_t = (float*)Ebf;                        // alias: E' dead after mlp1
    unsigned short* Hs = (unsigned short*)d_out;     // Hs then cand share d_out
    unsigned long long* cand = (unsigned long long*)d_out;

    // splitW first: it also zeroes counts/tileMax*/accums/partialZ/partialC
    k_splitW<<<512, 256, 0, stream>>>(w1, w2, W1s, W2s, counts,
                                      tileMaxC, tileMaxCl, accums, partialZ, partialC);
    // buildA also inits packed/packed2 (replaces memset)
    k_buildA<<<NTOK / 64, 256, 0, stream>>>(z, Ahi, Alo, zsq, sA, sB, partialZ,
                                            packed, packed2);
    k_buildE<<<KCB / 4, 256, 0, stream>>>(emb_w, Ebf);

    // MLP: Hs[k][768] = split(gelu(E' x W1s^T))  (codes on the M side)
    k_mlp<1><<<dim3(2, KCB / 128), 256, 0, stream>>>(Ebf, W1s, Hs, nullptr);
    // C_t[d][8192] = W2s x Hs^T
    k_mlp<0><<<dim3(KCB / 128, 2), 256, 0, stream>>>(W2s, Hs, nullptr, C_t);

    k_buildB<<<KCB / 64, 256, 0, stream>>>(C_t, Bhi, Blo, csq, sC, sCl,
                                           tileMaxC, tileMaxCl, accums, partialC);

    // Phase-1: d_hi GEMM (256x256 tiles, R1 structure, single dispatch)
    k_dist_hi<<<dim3(NTOK / 256, KCB / 256), 512, 0, stream>>>(
        Ahi, Bhi, zsq, csq, sA, sB, tileMaxC, tileMaxCl, packed, accums, cand);

    // Phase-2: exact rescore of survivors
    k_rescore<<<1024, 256, 0, stream>>>(cand, Ahi, Alo, Bhi, Blo, zsq, csq,
                                        sA, sB, sC, sCl, packed, packed2, accums);

    // zqloss (+fused unpack/counts)
    k_zqloss<<<BATCH * DIM, 256, 0, stream>>>(z, C_t, packed2, out, accums + 1, counts);
    k_scalars<<<1, 256, 0, stream>>>(counts, accums, zsq, csq, partialZ, partialC, out + OUTQ);
}

// Round 8
// 380.340 us; speedup vs baseline: 1.1673x; 1.0817x over previous
//
#include <hip/hip_runtime.h>
#include <math.h>

// Problem constants (fixed by setup_inputs)
#define BATCH 2
#define DIM   256
#define THW   8192            // T*H*W = 8*32*32
#define NTOK  16384           // BATCH*THW
#define KCB   8192            // codebook size
#define OUTQ  4194304         // BATCH*DIM*THW
#define CAP   2000000         // candidate buffer entries (16 MB in d_out)
#define SCAP  5600            // per-block LDS candidate staging capacity

typedef short short8 __attribute__((ext_vector_type(8)));
typedef float f32x4 __attribute__((ext_vector_type(4)));

__device__ __forceinline__ unsigned short f2bf_rn(float v) {
    unsigned u = __float_as_uint(v);
    unsigned r = u + 0x7FFFu + ((u >> 16) & 1u);
    return (unsigned short)(r >> 16);
}
__device__ __forceinline__ float bf2f(unsigned short b) {
    return __uint_as_float((unsigned)b << 16);
}
__device__ __forceinline__ void gl2lds16(const unsigned short* g, unsigned short* l) {
    __builtin_amdgcn_global_load_lds(
        (const __attribute__((address_space(1))) void*)g,
        (__attribute__((address_space(3))) void*)l, 16, 0, 0);
}

// ---------------------------------------------------------------------------
// splitW: w (row-major [256][256]) -> Ws [256][768] = [whi|whi|wlo].
// Runs FIRST; also folds in all the buffer zeroing that used to be
// hipMemsetAsync (counts, tileMax*, accums, partialZ/C pre-reduce arrays).
// ---------------------------------------------------------------------------
__global__ void k_splitW(const float* __restrict__ w1, const float* __restrict__ w2,
                         unsigned short* __restrict__ W1s, unsigned short* __restrict__ W2s,
                         int* __restrict__ counts,
                         unsigned* __restrict__ tileMaxC, unsigned* __restrict__ tileMaxCl,
                         float* __restrict__ accums,
                         float* __restrict__ partialZ, float* __restrict__ partialC) {
    int bid = blockIdx.x;
    int t = threadIdx.x;
    // housekeeping inits (replace the 3 hipMemsetAsync calls)
    if (bid < 32) {
        counts[bid * 256 + t] = 0;
    } else if (bid == 32) {
        if (t < 64) { tileMaxC[t] = 0u; tileMaxCl[t] = 0u; }
        if (t >= 64 && t < 72) accums[t - 64] = 0.f;
    } else if (bid == 33) {
        partialZ[t] = 0.f;
    } else if (bid == 34) {
        partialC[t] = 0.f;
    }
    int row = bid & 255;
    const float* src = (bid >> 8) ? w2 : w1;
    unsigned short* dst = ((bid >> 8) ? W2s : W1s) + (size_t)row * 768;
    float v = src[row * 256 + t];
    unsigned short hb = f2bf_rn(v);
    unsigned short lb = f2bf_rn(v - bf2f(hb));
    dst[t] = hb;
    dst[256 + t] = hb;
    dst[512 + t] = lb;
}

// ---------------------------------------------------------------------------
// buildA: z -> Ahi/Alo [NTOK][256]; zsq, sA=2.1*sqrt(zlosq), sB=2.1*sqrt(zsq);
// per-dim sums of z atomically into partialZ[256]; also inits packed/packed2
// rows to ~0 (replaces the 256 KB memset).
// ---------------------------------------------------------------------------
__global__ void k_buildA(const float* __restrict__ z,
                         unsigned short* __restrict__ Ahi,
                         unsigned short* __restrict__ Alo,
                         float* __restrict__ zsq,
                         float* __restrict__ sA, float* __restrict__ sB,
                         float* __restrict__ partialZ,
                         unsigned long long* __restrict__ packed,
                         unsigned long long* __restrict__ packed2) {
    __shared__ ushort2 tile[64][65];
    __shared__ float zacc[64];
    __shared__ float lacc[64];
    __shared__ float pz[256];
    int t = threadIdx.x;
    int n0 = blockIdx.x * 64;
    int b = n0 >> 13;
    int thw0 = n0 & 8191;
    if (t < 64) {
        zacc[t] = 0.f; lacc[t] = 0.f;
        packed[n0 + t] = ~0ull;
        packed2[n0 + t] = ~0ull;
    }
    pz[t] = 0.f;
    __syncthreads();
    int nn_r = t & 63, dg = t >> 6;
    float a1 = 0.f, a2 = 0.f;
    for (int dc = 0; dc < 256; dc += 64) {
        for (int r = 0; r < 16; ++r) {
            int dd = r * 4 + dg;
            float v = z[((size_t)(b * 256 + dc + dd)) * 8192 + thw0 + nn_r];
            unsigned short hb = f2bf_rn(v);
            float hf = bf2f(hb);
            unsigned short lb = f2bf_rn(v - hf);
            float lf = bf2f(lb);
            tile[dd][nn_r] = make_ushort2(hb, lb);
            a1 += v * v;
            a2 += lf * lf;
        }
        __syncthreads();
        int kk = t & 63, ng = t >> 6;
        float dimsum = 0.f;
        for (int i2 = 0; i2 < 16; ++i2) {
            int nn = ng + i2 * 4;
            ushort2 hl = tile[kk][nn];
            size_t base = (size_t)(n0 + nn) * 256;
            Ahi[base + dc + kk] = hl.x;
            Alo[base + dc + kk] = hl.y;
            dimsum += bf2f(hl.x) + bf2f(hl.y);
        }
        atomicAdd(&pz[dc + kk], dimsum);
        __syncthreads();
    }
    atomicAdd(&zacc[nn_r], a1);
    atomicAdd(&lacc[nn_r], a2);
    __syncthreads();
    if (t < 64) {
        zsq[n0 + t] = zacc[t];
        sA[n0 + t] = 2.1f * sqrtf(lacc[t]);
        sB[n0 + t] = 2.1f * sqrtf(zacc[t]);
    }
    atomicAdd(&partialZ[t], pz[t]);
}

// ---------------------------------------------------------------------------
// buildE: emb [8192][256] -> E' [8192][768] = [ehi|elo|ehi]
// ---------------------------------------------------------------------------
__global__ void k_buildE(const float* __restrict__ emb, unsigned short* __restrict__ E) {
    int t = threadIdx.x;
    int row = blockIdx.x * 4 + (t >> 6);
    int e4 = (t & 63) * 4;
    float4 v = *(const float4*)&emb[(size_t)row * 256 + e4];
    ushort4 hi, lo;
    hi.x = f2bf_rn(v.x); lo.x = f2bf_rn(v.x - bf2f(hi.x));
    hi.y = f2bf_rn(v.y); lo.y = f2bf_rn(v.y - bf2f(hi.y));
    hi.z = f2bf_rn(v.z); lo.z = f2bf_rn(v.z - bf2f(hi.z));
    hi.w = f2bf_rn(v.w); lo.w = f2bf_rn(v.w - bf2f(hi.w));
    size_t base = (size_t)row * 768;
    *(ushort4*)&E[base + e4] = hi;
    *(ushort4*)&E[base + 256 + e4] = lo;
    *(ushort4*)&E[base + 512 + e4] = hi;
}

// ---------------------------------------------------------------------------
// MLP GEMM on split-bf16 MFMA, 128x128 tiles, r3 2-barrier K-loop (12 kc).
// ---------------------------------------------------------------------------
template <int GELU>
__global__ __launch_bounds__(256) void k_mlp(const unsigned short* __restrict__ A,
                                             const unsigned short* __restrict__ B,
                                             unsigned short* __restrict__ Hs,
                                             float* __restrict__ C_t) {
    __shared__ __align__(16) char smem[32768];
    unsigned short* Asm = (unsigned short*)smem;
    unsigned short* Bsm = (unsigned short*)(smem + 16384);

    int t = threadIdx.x;
    int lane = t & 63;
    int w = t >> 6;
    int wm = w >> 1, wn = w & 1;
    int m0 = blockIdx.y * 128;
    int n0 = blockIdx.x * 128;

    int rA = w * 8 + (lane >> 3);
    int ch_l = lane & 7;
    int ch_g = ch_l ^ (lane >> 3);
    const unsigned short* gA = A + (size_t)(m0 + rA) * 768 + ch_g * 8;
    const unsigned short* gB = B + (size_t)(n0 + rA) * 768 + ch_g * 8;
    unsigned short* lA = &Asm[rA * 64 + ch_l * 8];
    unsigned short* lB = &Bsm[rA * 64 + ch_l * 8];

    f32x4 acc[4][4];
#pragma unroll
    for (int i = 0; i < 4; ++i)
#pragma unroll
        for (int j = 0; j < 4; ++j)
            acc[i][j] = f32x4{0.f, 0.f, 0.f, 0.f};

#pragma unroll
    for (int i = 0; i < 4; ++i) {
        gl2lds16(gA + (size_t)(32 * i) * 768, lA + 32 * i * 64);
        gl2lds16(gB + (size_t)(32 * i) * 768, lB + 32 * i * 64);
    }
    __syncthreads();

    int l15 = lane & 15;
    int quad = lane >> 4;
    int sw = l15 & 7;
    for (int kc = 0; kc < 12; ++kc) {
#pragma unroll
        for (int kk = 0; kk < 2; ++kk) {
            short8 a[4], b[4];
#pragma unroll
            for (int i = 0; i < 4; ++i)
                a[i] = *(const short8*)&Asm[(wm * 64 + i * 16 + l15) * 64 +
                                            (((kk * 4 + quad) ^ sw) * 8)];
#pragma unroll
            for (int j = 0; j < 4; ++j)
                b[j] = *(const short8*)&Bsm[(wn * 64 + j * 16 + l15) * 64 +
                                            (((kk * 4 + quad) ^ sw) * 8)];
#pragma unroll
            for (int i = 0; i < 4; ++i)
#pragma unroll
                for (int j = 0; j < 4; ++j)
                    acc[i][j] = __builtin_amdgcn_mfma_f32_16x16x32_bf16(a[i], b[j], acc[i][j], 0, 0, 0);
        }
        __syncthreads();
        if (kc < 11) {
            int ko = (kc + 1) * 64;
#pragma unroll
            for (int i = 0; i < 4; ++i) {
                gl2lds16(gA + (size_t)(32 * i) * 768 + ko, lA + 32 * i * 64);
                gl2lds16(gB + (size_t)(32 * i) * 768 + ko, lB + 32 * i * 64);
            }
            __syncthreads();
        }
    }

    // epilogue: C/D layout col=lane&15, row=quad*4+reg
#pragma unroll
    for (int i = 0; i < 4; ++i) {
#pragma unroll
        for (int reg = 0; reg < 4; ++reg) {
            int mrow = m0 + wm * 64 + i * 16 + quad * 4 + reg;
#pragma unroll
            for (int j = 0; j < 4; ++j) {
                int ncol = n0 + wn * 64 + j * 16 + l15;
                float h = acc[i][j][reg];
                if (GELU) {
                    float g = 0.5f * h * (1.f + erff(h * 0.70710678118654752f));
                    unsigned short hb = f2bf_rn(g);
                    unsigned short lb = f2bf_rn(g - bf2f(hb));
                    size_t base = (size_t)mrow * 768;
                    Hs[base + ncol] = hb;
                    Hs[base + 256 + ncol] = lb;
                    Hs[base + 512 + ncol] = hb;
                } else {
                    C_t[(size_t)mrow * 8192 + ncol] = h;
                }
            }
        }
    }
}

// ---------------------------------------------------------------------------
// buildB: C_t [256][8192] -> Bhi/Blo [KCB][256]; csq, sC, sCl; per-128-tile
// maxima of sC/sCl; global maxima into accums[3]/[4]; per-dim sums atomically
// into partialC[256].
// ---------------------------------------------------------------------------
__global__ void k_buildB(const float* __restrict__ C_t,
                         unsigned short* __restrict__ Bhi,
                         unsigned short* __restrict__ Blo,
                         float* __restrict__ csq,
                         float* __restrict__ sC, float* __restrict__ sCl,
                         unsigned* __restrict__ tileMaxC, unsigned* __restrict__ tileMaxCl,
                         float* __restrict__ accums, float* __restrict__ partialC) {
    __shared__ ushort2 tile[64][65];
    __shared__ float kacc[64];
    __shared__ float lacc[64];
    __shared__ float pc[256];
    int t = threadIdx.x;
    int k0 = blockIdx.x * 64;
    if (t < 64) { kacc[t] = 0.f; lacc[t] = 0.f; }
    pc[t] = 0.f;
    __syncthreads();
    int nn_r = t & 63, dg = t >> 6;
    float a1 = 0.f, a2 = 0.f;
    for (int dc = 0; dc < 256; dc += 64) {
        for (int r = 0; r < 16; ++r) {
            int dd = r * 4 + dg;
            float v = C_t[(size_t)(dc + dd) * KCB + k0 + nn_r];
            unsigned short hb = f2bf_rn(v);
            float hf = bf2f(hb);
            unsigned short lb = f2bf_rn(v - hf);
            float lf = bf2f(lb);
            tile[dd][nn_r] = make_ushort2(hb, lb);
            a1 += v * v;
            a2 += lf * lf;
        }
        __syncthreads();
        int kk = t & 63, ng = t >> 6;
        float dimsum = 0.f;
        for (int i2 = 0; i2 < 16; ++i2) {
            int nn = ng + i2 * 4;
            ushort2 hl = tile[kk][nn];
            size_t base = (size_t)(k0 + nn) * 256;
            Bhi[base + dc + kk] = hl.x;
            Blo[base + dc + kk] = hl.y;
            dimsum += bf2f(hl.x) + bf2f(hl.y);
        }
        atomicAdd(&pc[dc + kk], dimsum);
        __syncthreads();
    }
    atomicAdd(&kacc[nn_r], a1);
    atomicAdd(&lacc[nn_r], a2);
    __syncthreads();
    if (t < 64) {
        float c2 = kacc[t], l2 = lacc[t];
        float sc = sqrtf(c2), sl = sqrtf(l2);
        csq[k0 + t] = c2;
        sC[k0 + t] = sc;
        sCl[k0 + t] = sl;
        int tl = blockIdx.x >> 1;
        atomicMax(&tileMaxC[tl], __float_as_uint(sc));
        atomicMax(&tileMaxCl[tl], __float_as_uint(sl));
        atomicMax((unsigned*)&accums[3], __float_as_uint(c2));
        atomicMax((unsigned*)&accums[4], __float_as_uint(l2));
    }
    atomicAdd(&partialC[t], pc[t]);
}

// ---------------------------------------------------------------------------
// Phase-1: d_hi GEMM, BM=256 x BN=256, 512 threads (8 waves), BK=64, 4 kc.
// R1-verbatim structure (137 us measured): 2 x 64 KB LDS dbuf, stage(kc+1)
// issued BEFORE the compute of kc, one __syncthreads per kc. Single 2048-
// block dispatch (block-scheduling serialization populates packed[] for
// later blocks -> tight thresholds; splitting the dispatch broke this, R6).
// Value-only row-min; slim 2-pass epilogue + LDS-staged candidate appends.
// ---------------------------------------------------------------------------
__global__ __launch_bounds__(512, 2) void k_dist_hi(const unsigned short* __restrict__ A,
                                                    const unsigned short* __restrict__ B,
                                                    const float* __restrict__ zsq,
                                                    const float* __restrict__ csq,
                                                    const float* __restrict__ sA,
                                                    const float* __restrict__ sB,
                                                    const unsigned* __restrict__ tileMaxC,
                                                    const unsigned* __restrict__ tileMaxCl,
                                                    unsigned long long* __restrict__ packed,
                                                    float* __restrict__ accums,
                                                    unsigned long long* __restrict__ cand) {
    __shared__ __align__(16) char smem[131072];
    // buffer set b (b=0,1) at ushort offset b*32768:
    //   A [256][64] ushort (32 KB) at +0, B [256][64] (32 KB) at +16384
    // epilogue aliases (valid only after the final K-loop barrier):
    float* sbd     = (float*)smem;                   // [2][256]  0..2048
    float* gprev_s = (float*)(smem + 2048);          // [256]
    float* thr     = (float*)(smem + 3072);          // [256]
    unsigned* scnt  = (unsigned*)(smem + 4096);
    unsigned* sbase = (unsigned*)(smem + 4100);
    unsigned long long* scand = (unsigned long long*)(smem + 4112); // [SCAP]

    int t = threadIdx.x;
    int lane = t & 63;
    int w = t >> 6;                 // 0..7
    int wm = w >> 1, wn = w & 1;    // wm 0..3 (64 rows each), wn 0..1 (128 cols each)
    int m0 = blockIdx.x * 256;
    int n0 = blockIdx.y * 256;

    // staging addresses (LDS-linear dest + source chunk swizzle)
    int rA0 = w * 8 + (lane >> 3);  // 0..63
    int ch_l = lane & 7;
    int ch_g = ch_l ^ (lane >> 3);
    const unsigned short* gA = A + (size_t)(m0 + rA0) * 256 + ch_g * 8;
    const unsigned short* gB = B + (size_t)(n0 + rA0) * 256 + ch_g * 8;
    unsigned short* smemU = (unsigned short*)smem;
    unsigned short* lA = smemU + rA0 * 64 + ch_l * 8;           // within buf0 A
    unsigned short* lB = smemU + 16384 + rA0 * 64 + ch_l * 8;   // within buf0 B

    int l15 = lane & 15;
    int quad = lane >> 4;
    int sw = l15 & 7;

    // hoisted uniform epilogue constants
    float M1 = sqrtf(accums[3]);
    float M2 = sqrtf(accums[4]);
    float msC  = fmaxf(__uint_as_float(tileMaxC[2 * blockIdx.y]),
                       __uint_as_float(tileMaxC[2 * blockIdx.y + 1]));
    float msCl = fmaxf(__uint_as_float(tileMaxCl[2 * blockIdx.y]),
                       __uint_as_float(tileMaxCl[2 * blockIdx.y + 1]));
    float cv[8];
    int cols[8];
#pragma unroll
    for (int j = 0; j < 8; ++j) {
        int cloc = wn * 128 + j * 16 + l15;
        cols[j] = n0 + cloc;
        cv[j] = csq[cols[j]];
    }

    f32x4 acc[4][8];
#pragma unroll
    for (int i = 0; i < 4; ++i)
#pragma unroll
        for (int j = 0; j < 8; ++j)
            acc[i][j] = f32x4{0.f, 0.f, 0.f, 0.f};

    // stage buffer set B_ with K-offset KO (elements): 8 gl2lds per thread
#define STAGE(B_, KO)                                                       \
    {                                                                       \
        int off_ = (B_) * 32768;                                            \
        _Pragma("unroll")                                                   \
        for (int i_ = 0; i_ < 4; ++i_)                                      \
            gl2lds16(gA + (size_t)(64 * i_) * 256 + (KO),                   \
                     lA + off_ + 64 * i_ * 64);                             \
        _Pragma("unroll")                                                   \
        for (int i_ = 0; i_ < 4; ++i_)                                      \
            gl2lds16(gB + (size_t)(64 * i_) * 256 + (KO),                   \
                     lB + off_ + 64 * i_ * 64);                             \
    }

    // prologue: stage kc=0 into buf 0
    STAGE(0, 0)
    __syncthreads();   // kc=0 tile landed

    int cur = 0;
    for (int kc = 0; kc < 4; ++kc) {
        // issue next stage into the other buffer BEFORE compute
        if (kc < 3) STAGE(cur ^ 1, (kc + 1) * 64)
        const unsigned short* Ar = smemU + cur * 32768;
        const unsigned short* Br = Ar + 16384;
#pragma unroll
        for (int kk = 0; kk < 2; ++kk) {
            short8 a[4], b[8];
#pragma unroll
            for (int i = 0; i < 4; ++i)
                a[i] = *(const short8*)&Ar[(wm * 64 + i * 16 + l15) * 64 +
                                            (((kk * 4 + quad) ^ sw) * 8)];
#pragma unroll
            for (int j = 0; j < 8; ++j)
                b[j] = *(const short8*)&Br[(wn * 128 + j * 16 + l15) * 64 +
                                            (((kk * 4 + quad) ^ sw) * 8)];
#pragma unroll
            for (int i = 0; i < 4; ++i)
#pragma unroll
                for (int j = 0; j < 8; ++j)
                    acc[i][j] = __builtin_amdgcn_mfma_f32_16x16x32_bf16(a[i], b[j], acc[i][j], 0, 0, 0);
        }
        __syncthreads();
        cur ^= 1;
    }
#undef STAGE

    // ---- pass 1: transform in place + value-only per-row min
    if (t == 0) *scnt = 0;
    if (t < 256) {
        const unsigned* hp = (const unsigned*)&packed[m0 + t];
        gprev_s[t] = __uint_as_float(__atomic_load_n(hp + 1, __ATOMIC_RELAXED));
    }
#pragma unroll
    for (int i = 0; i < 4; ++i) {
#pragma unroll
        for (int reg = 0; reg < 4; ++reg) {
            int rloc = wm * 64 + i * 16 + quad * 4 + reg;
            float zs = zsq[m0 + rloc];
            float bd = 3.4e38f;
#pragma unroll
            for (int j = 0; j < 8; ++j) {
                float d = (zs + cv[j]) - 2.0f * acc[i][j][reg];
                acc[i][j][reg] = d;
                bd = fminf(bd, d);
            }
#pragma unroll
            for (int off = 1; off < 16; off <<= 1)
                bd = fminf(bd, __shfl_xor(bd, off, 64));
            if (l15 == 0) sbd[wn * 256 + rloc] = bd;
        }
    }
    __syncthreads();
    // ---- t<256: merge halves, global min (fire-and-forget), row threshold
    if (t < 256) {
        float bd = fminf(sbd[t], sbd[256 + t]);
        atomicMin(&packed[m0 + t], (unsigned long long)__float_as_uint(bd) << 32);
        float g = fminf(bd, gprev_s[t]);
        thr[t] = g + 1e-3f + sA[m0 + t] * (M1 + msC) + sB[m0 + t] * (M2 + msCl);
    }
    __syncthreads();
    // ---- pass 2: 1-compare filter + staged appends
    unsigned* cnt = (unsigned*)&accums[2];
#pragma unroll
    for (int i = 0; i < 4; ++i) {
#pragma unroll
        for (int reg = 0; reg < 4; ++reg) {
            int rloc = wm * 64 + i * 16 + quad * 4 + reg;
            float tr = thr[rloc];
            bool p[8];
            bool any = false;
#pragma unroll
            for (int j = 0; j < 8; ++j) {
                p[j] = acc[i][j][reg] <= tr;
                any |= p[j];
            }
            if (__ballot(any)) {
                unsigned rbits = (unsigned)((m0 + rloc) << 13);
#pragma unroll
                for (int j = 0; j < 8; ++j) {
                    if (p[j]) {
                        unsigned long long entry =
                            ((unsigned long long)__float_as_uint(acc[i][j][reg]) << 32) |
                            (rbits | (unsigned)cols[j]);
                        unsigned pos = atomicAdd(scnt, 1u);
                        if (pos < SCAP) scand[pos] = entry;
                        else {
                            unsigned gp2 = atomicAdd(cnt, 1u);
                            if (gp2 < CAP) cand[gp2] = entry;
                        }
                    }
                }
            }
        }
    }
    __syncthreads();
    if (t == 0) {
        unsigned m = *scnt;
        if (m > SCAP) m = SCAP;
        *scnt = m;
        *sbase = atomicAdd(cnt, m);
    }
    __syncthreads();
    {
        unsigned m = *scnt, b0 = *sbase;
        for (unsigned u = t; u < m; u += 512)
            if (b0 + u < CAP) cand[b0 + u] = scand[u];
    }
}

// ---------------------------------------------------------------------------
// Phase-2: two-phase rescore. Prefilter is LANE-PARALLEL (one candidate per
// THREAD, 64 in flight per wave -- the old one-candidate-per-WAVE loop was
// latency-bound: ~166 sequential scattered-load rounds per wave). Survivors
// are ballot-compacted into an LDS queue (<=256/chunk, no overflow), then
// the block's 4 waves cooperatively run the exact 64-lane dot product on
// each queued entry. Same math, same lex atomicMin.
// ---------------------------------------------------------------------------
__global__ __launch_bounds__(256) void k_rescore(const unsigned long long* __restrict__ cand,
                                                 const unsigned short* __restrict__ Ahi,
                                                 const unsigned short* __restrict__ Alo,
                                                 const unsigned short* __restrict__ Bhi,
                                                 const unsigned short* __restrict__ Blo,
                                                 const float* __restrict__ zsq,
                                                 const float* __restrict__ csq,
                                                 const float* __restrict__ sA,
                                                 const float* __restrict__ sB,
                                                 const float* __restrict__ sC,
                                                 const float* __restrict__ sCl,
                                                 const unsigned long long* __restrict__ packed,
                                                 unsigned long long* __restrict__ packed2,
                                                 const float* __restrict__ accums) {
    __shared__ unsigned long long q[256];
    __shared__ unsigned qn;
    unsigned total = *(const unsigned*)&accums[2];
    if (total > CAP) total = CAP;
    float M1 = sqrtf(accums[3]);
    float M2 = sqrtf(accums[4]);
    int t = threadIdx.x;
    int lane = t & 63;
    int w = t >> 6;
    unsigned per = (total + gridDim.x - 1) / gridDim.x;
    unsigned e0 = blockIdx.x * per;
    unsigned e1 = e0 + per;
    if (e1 > total) e1 = total;
    for (unsigned base = e0; base < e1; base += 256) {
        if (t == 0) qn = 0;
        __syncthreads();
        // phase 1: lane-parallel prefilter of up to 256 entries
        unsigned e = base + (unsigned)t;
        bool pass = false;
        unsigned long long ent = 0;
        if (e < e1) {
            ent = cand[e];
            float dhi = __uint_as_float((unsigned)(ent >> 32));
            unsigned nk = (unsigned)ent;
            int n = (nk >> 13) & 16383;
            int k = nk & 8191;
            float g = __uint_as_float((unsigned)(packed[n] >> 32));
            float marg = g + 1e-3f + sA[n] * (M1 + sC[k]) + sB[n] * (M2 + sCl[k]);
            pass = (dhi <= marg);
        }
        unsigned long long mask = __ballot(pass);
        if (mask) {
            unsigned cw = (unsigned)__popcll(mask);
            unsigned wbase = 0;
            if (lane == 0) wbase = atomicAdd(&qn, cw);
            wbase = __shfl(wbase, 0, 64);
            if (pass) {
                unsigned pos = wbase +
                    (unsigned)__popcll(mask & ((1ull << lane) - 1ull));
                q[pos] = ent;
            }
        }
        __syncthreads();
        // phase 2: wave-cooperative exact rescore of survivors
        unsigned m = qn;
        for (unsigned i = (unsigned)w; i < m; i += 4) {
            unsigned long long e2 = q[i];
            unsigned nk = (unsigned)e2;
            int n = (nk >> 13) & 16383;
            int k = nk & 8191;
            ushort4 zh = *((const ushort4*)(Ahi + (size_t)n * 256) + lane);
            ushort4 zl = *((const ushort4*)(Alo + (size_t)n * 256) + lane);
            ushort4 ch = *((const ushort4*)(Bhi + (size_t)k * 256) + lane);
            ushort4 cl = *((const ushort4*)(Blo + (size_t)k * 256) + lane);
            float s = (bf2f(zh.x) + bf2f(zl.x)) * (bf2f(ch.x) + bf2f(cl.x))
                    + (bf2f(zh.y) + bf2f(zl.y)) * (bf2f(ch.y) + bf2f(cl.y))
                    + (bf2f(zh.z) + bf2f(zl.z)) * (bf2f(ch.z) + bf2f(cl.z))
                    + (bf2f(zh.w) + bf2f(zl.w)) * (bf2f(ch.w) + bf2f(cl.w));
#pragma unroll
            for (int off = 1; off < 64; off <<= 1)
                s += __shfl_xor(s, off, 64);
            if (lane == 0) {
                float dd = (zsq[n] + csq[k]) - 2.0f * s;
                unsigned long long p =
                    ((unsigned long long)__float_as_uint(dd) << 32) | (unsigned)k;
                atomicMin(&packed2[n], p);
            }
        }
        __syncthreads();   // q/qn reuse safe for next chunk
    }
}

// ---------------------------------------------------------------------------
// zqloss (+fused unpack): reads packed2 directly for code indices, gathers
// codebook rows, writes out, accumulates VQ loss. Counts histogram spread
// evenly: each of the 512 blocks histograms 32 tokens (no straggler blocks).
// ---------------------------------------------------------------------------
__global__ void k_zqloss(const float* __restrict__ z, const float* __restrict__ C_t,
                         const unsigned long long* __restrict__ packed2,
                         float* __restrict__ out, float* __restrict__ loss_sum,
                         int* __restrict__ counts) {
    __shared__ float red[256];
    int bid = blockIdx.x;
    int b = bid >> 8;
    int d = bid & 255;
    int t = threadIdx.x;
    // evenly-spread histogram: 512 blocks x 32 tokens = 16384
    if (t < 32) {
        int kk = (int)(unsigned)packed2[bid * 32 + t] & 8191;
        atomicAdd(&counts[kk], 1);
    }
    const float* crow = C_t + (size_t)d * KCB;
    const unsigned long long* pb = packed2 + (size_t)b * THW;
    size_t base = ((size_t)(b * DIM + d)) * THW;
    float lsum = 0.f;
    for (int it = 0; it < 8; ++it) {
        int thw = it * 1024 + t * 4;
        ulonglong2 p01 = *(const ulonglong2*)&pb[thw];
        ulonglong2 p23 = *(const ulonglong2*)&pb[thw + 2];
        int i0 = (int)(unsigned)p01.x & 8191;
        int i1 = (int)(unsigned)p01.y & 8191;
        int i2 = (int)(unsigned)p23.x & 8191;
        int i3 = (int)(unsigned)p23.y & 8191;
        float4 zz = *(const float4*)&z[base + thw];
        float4 v;
        v.x = crow[i0]; v.y = crow[i1]; v.z = crow[i2]; v.w = crow[i3];
        *(float4*)&out[base + thw] = v;
        float d0 = v.x - zz.x, d1 = v.y - zz.y, d2 = v.z - zz.z, d3 = v.w - zz.w;
        lsum += d0 * d0 + d1 * d1 + d2 * d2 + d3 * d3;
    }
    red[t] = lsum;
    __syncthreads();
    for (int s = 128; s > 0; s >>= 1) {
        if (t < s) red[t] += red[t + s];
        __syncthreads();
    }
    if (t == 0) atomicAdd(loss_sum, red[0]);
}

// ---------------------------------------------------------------------------
// Final scalars: loss, perplexity, closed-form mean_distance.
// partialZ/partialC are already fully reduced [256] arrays.
// ---------------------------------------------------------------------------
__global__ void k_scalars(const int* __restrict__ counts,
                          const float* __restrict__ accums,
                          const float* __restrict__ zsq, const float* __restrict__ csq,
                          const float* __restrict__ partialZ,
                          const float* __restrict__ partialC,
                          float* __restrict__ out_tail) {
    __shared__ double redd[256];
    __shared__ float redf[256];
    int t = threadIdx.x;
    double szsq = 0.0, scsq = 0.0;
    for (int n = t; n < NTOK; n += 256) szsq += (double)zsq[n];
    for (int k = t; k < KCB; k += 256) scsq += (double)csq[k];
    float SZ = partialZ[t];
    float SC = partialC[t];
    double total = 8192.0 * szsq + 16384.0 * scsq - 2.0 * (double)SZ * (double)SC;
    redd[t] = total;
    float s = 0.f;
    for (int k = t; k < KCB; k += 256) {
        float e = (float)counts[k] * (1.0f / 16384.0f);
        s += e * logf(e + 1e-10f);
    }
    redf[t] = s;
    __syncthreads();
    for (int st = 128; st > 0; st >>= 1) {
        if (t < st) { redd[t] += redd[t + st]; redf[t] += redf[t + st]; }
        __syncthreads();
    }
    if (t == 0) {
        out_tail[0] = 1.25f * accums[1] / 4194304.0f;
        out_tail[1] = expf(-redf[0]);
        out_tail[2] = (float)(redd[0] / (16384.0 * 8192.0));
    }
}

// ---------------------------------------------------------------------------
extern "C" void kernel_launch(void* const* d_in, const int* in_sizes, int n_in,
                              void* d_out, int out_size, void* d_ws, size_t ws_size,
                              hipStream_t stream) {
    const float* z     = (const float*)d_in[0];   // [2][256][8192]
    const float* emb_w = (const float*)d_in[1];   // [8192][256]
    const float* w1    = (const float*)d_in[2];   // [256][256]
    const float* w2    = (const float*)d_in[3];   // [256][256]
    float* out = (float*)d_out;

    char* w = (char*)d_ws;
    unsigned short* Ahi = (unsigned short*)(w + 0);          //  8,388,608
    unsigned short* Alo = (unsigned short*)(w + 8388608);    //  8,388,608
    unsigned short* Ebf = (unsigned short*)(w + 16777216);   // 12,582,912 (E'; C_t aliases after mlp1)
    unsigned short* Bhi = (unsigned short*)(w + 29360128);   //  4,194,304
    unsigned short* Blo = (unsigned short*)(w + 33554432);   //  4,194,304
    unsigned short* W1s = (unsigned short*)(w + 37748736);   //    393,216
    unsigned short* W2s = (unsigned short*)(w + 38141952);   //    393,216
    float* zsq   = (float*)(w + 38535168);   // 65,536
    float* sA    = (float*)(w + 38666240);   // 65,536
    float* sB    = (float*)(w + 38731776);   // 65,536
    float* csq   = (float*)(w + 38797312);   // 32,768
    float* sC    = (float*)(w + 38862848);   // 32,768
    float* sCl   = (float*)(w + 38895616);   // 32,768
    unsigned long long* packed  = (unsigned long long*)(w + 38928384); // 131,072
    unsigned long long* packed2 = (unsigned long long*)(w + 39059456); // 131,072
    int*   counts = (int*)(w + 39256064);    // 32,768
    float* partialZ = (float*)(w + 39288832); // [256] pre-reduced
    float* partialC = (float*)(w + 39550976); // [256] pre-reduced
    unsigned* tileMaxC  = (unsigned*)(w + 39682048); // 256
    unsigned* tileMaxCl = (unsigned*)(w + 39682304); // 256
    float* accums = (float*)(w + 39682560);  // [1]loss [2]cnt [3]csqmax [4]closqmax

    float* C_t = (float*)Ebf;                        // alias: E' dead after mlp1
    unsigned short* Hs = (unsigned short*)d_out;     // Hs then cand share d_out
    unsigned long long* cand = (unsigned long long*)d_out;

    // splitW first: it also zeroes counts/tileMax*/accums/partialZ/partialC
    k_splitW<<<512, 256, 0, stream>>>(w1, w2, W1s, W2s, counts,
                                      tileMaxC, tileMaxCl, accums, partialZ, partialC);
    // buildA also inits packed/packed2 (replaces memset)
    k_buildA<<<NTOK / 64, 256, 0, stream>>>(z, Ahi, Alo, zsq, sA, sB, partialZ,
                                            packed, packed2);
    k_buildE<<<KCB / 4, 256, 0, stream>>>(emb_w, Ebf);

    // MLP: Hs[k][768] = split(gelu(E' x W1s^T))  (codes on the M side)
    k_mlp<1><<<dim3(2, KCB / 128), 256, 0, stream>>>(Ebf, W1s, Hs, nullptr);
    // C_t[d][8192] = W2s x Hs^T
    k_mlp<0><<<dim3(KCB / 128, 2), 256, 0, stream>>>(W2s, Hs, nullptr, C_t);

    k_buildB<<<KCB / 64, 256, 0, stream>>>(C_t, Bhi, Blo, csq, sC, sCl,
                                           tileMaxC, tileMaxCl, accums, partialC);

    // Phase-1: d_hi GEMM (256x256 tiles, R1 structure, single dispatch)
    k_dist_hi<<<dim3(NTOK / 256, KCB / 256), 512, 0, stream>>>(
        Ahi, Bhi, zsq, csq, sA, sB, tileMaxC, tileMaxCl, packed, accums, cand);

    // Phase-2: two-phase rescore (lane-parallel prefilter + wave rescore)
    k_rescore<<<1024, 256, 0, stream>>>(cand, Ahi, Alo, Bhi, Blo, zsq, csq,
                                        sA, sB, sC, sCl, packed, packed2, accums);

    // zqloss (+fused histogram, evenly spread)
    k_zqloss<<<BATCH * DIM, 256, 0, stream>>>(z, C_t, packed2, out, accums + 1, counts);
    k_scalars<<<1, 256, 0, stream>>>(counts, accums, zsq, csq, partialZ, partialC, out + OUTQ);
}

// Round 9
// 355.671 us; speedup vs baseline: 1.2482x; 1.0694x over previous
//
#include <hip/hip_runtime.h>
#include <math.h>

// Problem constants (fixed by setup_inputs)
#define BATCH 2
#define DIM   256
#define THW   8192            // T*H*W = 8*32*32
#define NTOK  16384           // BATCH*THW
#define KCB   8192            // codebook size
#define OUTQ  4194304         // BATCH*DIM*THW
#define CAP   2000000         // candidate buffer entries (16 MB in d_out)
#define SCAP  5600            // per-block LDS candidate staging capacity

typedef short short8 __attribute__((ext_vector_type(8)));
typedef float f32x4 __attribute__((ext_vector_type(4)));

__device__ __forceinline__ unsigned short f2bf_rn(float v) {
    unsigned u = __float_as_uint(v);
    unsigned r = u + 0x7FFFu + ((u >> 16) & 1u);
    return (unsigned short)(r >> 16);
}
__device__ __forceinline__ float bf2f(unsigned short b) {
    return __uint_as_float((unsigned)b << 16);
}
__device__ __forceinline__ void gl2lds16(const unsigned short* g, unsigned short* l) {
    __builtin_amdgcn_global_load_lds(
        (const __attribute__((address_space(1))) void*)g,
        (__attribute__((address_space(3))) void*)l, 16, 0, 0);
}

// ---------------------------------------------------------------------------
// prep: one launch fusing three independent preprocessing kernels
//   bid 0..511   : splitW  (w1/w2 -> W1s/W2s [256][768]=[hi|hi|lo])
//                  + housekeeping zeroing (counts/tileMax/accums/partials)
//   bid 512..767 : buildA  (z -> Ahi/Alo, zsq/sA/sB, partialZ, packed init)
//   bid 768..2815: buildE  (emb -> E' [8192][768]=[hi|lo|hi])
// ---------------------------------------------------------------------------
__global__ void k_prep(const float* __restrict__ w1, const float* __restrict__ w2,
                       unsigned short* __restrict__ W1s, unsigned short* __restrict__ W2s,
                       int* __restrict__ counts,
                       unsigned* __restrict__ tileMaxC, unsigned* __restrict__ tileMaxCl,
                       float* __restrict__ accums,
                       float* __restrict__ partialZ, float* __restrict__ partialC,
                       const float* __restrict__ z,
                       unsigned short* __restrict__ Ahi, unsigned short* __restrict__ Alo,
                       float* __restrict__ zsq, float* __restrict__ sA, float* __restrict__ sB,
                       unsigned long long* __restrict__ packed,
                       unsigned long long* __restrict__ packed2,
                       const float* __restrict__ emb, unsigned short* __restrict__ E) {
    __shared__ ushort2 tile[64][65];
    __shared__ float zacc[64];
    __shared__ float lacc[64];
    __shared__ float pz[256];
    int bid = blockIdx.x;
    int t = threadIdx.x;

    if (bid < 512) {
        // ---- splitW + housekeeping ----
        if (bid < 32) {
            counts[bid * 256 + t] = 0;
        } else if (bid == 32) {
            if (t < 64) { tileMaxC[t] = 0u; tileMaxCl[t] = 0u; }
            if (t >= 64 && t < 72) accums[t - 64] = 0.f;
        } else if (bid == 33) {
            partialZ[t] = 0.f;
        } else if (bid == 34) {
            partialC[t] = 0.f;
        }
        int row = bid & 255;
        const float* src = (bid >> 8) ? w2 : w1;
        unsigned short* dst = ((bid >> 8) ? W2s : W1s) + (size_t)row * 768;
        float v = src[row * 256 + t];
        unsigned short hb = f2bf_rn(v);
        unsigned short lb = f2bf_rn(v - bf2f(hb));
        dst[t] = hb;
        dst[256 + t] = hb;
        dst[512 + t] = lb;
        return;
    }
    if (bid >= 768) {
        // ---- buildE ----
        int row = (bid - 768) * 4 + (t >> 6);
        int e4 = (t & 63) * 4;
        float4 v = *(const float4*)&emb[(size_t)row * 256 + e4];
        ushort4 hi, lo;
        hi.x = f2bf_rn(v.x); lo.x = f2bf_rn(v.x - bf2f(hi.x));
        hi.y = f2bf_rn(v.y); lo.y = f2bf_rn(v.y - bf2f(hi.y));
        hi.z = f2bf_rn(v.z); lo.z = f2bf_rn(v.z - bf2f(hi.z));
        hi.w = f2bf_rn(v.w); lo.w = f2bf_rn(v.w - bf2f(hi.w));
        size_t base = (size_t)row * 768;
        *(ushort4*)&E[base + e4] = hi;
        *(ushort4*)&E[base + 256 + e4] = lo;
        *(ushort4*)&E[base + 512 + e4] = hi;
        return;
    }
    // ---- buildA ----
    int n0 = (bid - 512) * 64;
    int b = n0 >> 13;
    int thw0 = n0 & 8191;
    if (t < 64) {
        zacc[t] = 0.f; lacc[t] = 0.f;
        packed[n0 + t] = ~0ull;
        packed2[n0 + t] = ~0ull;
    }
    pz[t] = 0.f;
    __syncthreads();
    int nn_r = t & 63, dg = t >> 6;
    float a1 = 0.f, a2 = 0.f;
    for (int dc = 0; dc < 256; dc += 64) {
        for (int r = 0; r < 16; ++r) {
            int dd = r * 4 + dg;
            float v = z[((size_t)(b * 256 + dc + dd)) * 8192 + thw0 + nn_r];
            unsigned short hb = f2bf_rn(v);
            float hf = bf2f(hb);
            unsigned short lb = f2bf_rn(v - hf);
            float lf = bf2f(lb);
            tile[dd][nn_r] = make_ushort2(hb, lb);
            a1 += v * v;
            a2 += lf * lf;
        }
        __syncthreads();
        int kk = t & 63, ng = t >> 6;
        float dimsum = 0.f;
        for (int i2 = 0; i2 < 16; ++i2) {
            int nn = ng + i2 * 4;
            ushort2 hl = tile[kk][nn];
            size_t base = (size_t)(n0 + nn) * 256;
            Ahi[base + dc + kk] = hl.x;
            Alo[base + dc + kk] = hl.y;
            dimsum += bf2f(hl.x) + bf2f(hl.y);
        }
        atomicAdd(&pz[dc + kk], dimsum);
        __syncthreads();
    }
    atomicAdd(&zacc[nn_r], a1);
    atomicAdd(&lacc[nn_r], a2);
    __syncthreads();
    if (t < 64) {
        zsq[n0 + t] = zacc[t];
        sA[n0 + t] = 2.1f * sqrtf(lacc[t]);
        sB[n0 + t] = 2.1f * sqrtf(zacc[t]);
    }
    atomicAdd(&partialZ[t], pz[t]);
}

// ---------------------------------------------------------------------------
// MLP GEMM on split-bf16 MFMA. v2: BM=64 x BN=128, BK=64, 12 kc, 256 thr
// (4 waves 2x2, wave tile 32x64, acc[2][4] = 32 AGPR). 256 blocks -> full
// GPU (v1 had 128 blocks = half idle). R1-style LDS double-buffer: stage
// (kc+1) issued BEFORE compute(kc), one barrier per kc (v1 was single-
// buffered: fully serial stage-drain -> compute per kc). Staging respects
// the gl2lds wave-uniform-base + lane*16B rule (each wave stages 8
// contiguous 128B rows; source chunk pre-swizzled ch^(row&7)).
// K-accumulation order per output is unchanged vs v1 -> bit-identical.
// GELU=1 (mlp1): Hs[code][768] = split(gelu(h)); GELU=0 (mlp2): C_t.
// ---------------------------------------------------------------------------
template <int GELU>
__global__ __launch_bounds__(256) void k_mlp(const unsigned short* __restrict__ A,
                                             const unsigned short* __restrict__ B,
                                             unsigned short* __restrict__ Hs,
                                             float* __restrict__ C_t) {
    __shared__ __align__(16) char smem[49152];
    unsigned short* smemU = (unsigned short*)smem;
    // buf b at ushort offset b*12288: A [64][64] at +0, B [128][64] at +4096

    int t = threadIdx.x;
    int lane = t & 63;
    int w = t >> 6;
    int wm = w >> 1, wn = w & 1;        // wave tile 32(m) x 64(n)
    int m0 = blockIdx.y * 64;
    int n0 = blockIdx.x * 128;

    // staging: wave w stages rows w*8+(lane>>3) (+32k); chunk lane&7,
    // source chunk pre-swizzled so LDS stays linear (lane*16B per wave run)
    int rA0 = w * 8 + (lane >> 3);      // 0..31
    int ch_l = lane & 7;
    int ch_g = ch_l ^ (rA0 & 7);        // (rA0+32g)&7 == rA0&7
    const unsigned short* gA = A + (size_t)(m0 + rA0) * 768 + ch_g * 8;
    const unsigned short* gB = B + (size_t)(n0 + rA0) * 768 + ch_g * 8;
    int lds0 = rA0 * 64 + ch_l * 8;

    f32x4 acc[2][4];
#pragma unroll
    for (int i = 0; i < 2; ++i)
#pragma unroll
        for (int j = 0; j < 4; ++j)
            acc[i][j] = f32x4{0.f, 0.f, 0.f, 0.f};

#define MSTAGE(BUF, KO)                                                     \
    {                                                                       \
        unsigned short* ba_ = smemU + (BUF) * 12288;                        \
        gl2lds16(gA + (KO), ba_ + lds0);                                    \
        gl2lds16(gA + (KO) + (size_t)32 * 768, ba_ + 2048 + lds0);          \
        _Pragma("unroll")                                                   \
        for (int g_ = 0; g_ < 4; ++g_)                                      \
            gl2lds16(gB + (KO) + (size_t)(32 * g_) * 768,                   \
                     ba_ + 4096 + g_ * 2048 + lds0);                        \
    }

    MSTAGE(0, 0)
    __syncthreads();

    int l15 = lane & 15;
    int quad = lane >> 4;
    int sw = l15 & 7;
    int cur = 0;
    for (int kc = 0; kc < 12; ++kc) {
        if (kc < 11) MSTAGE(cur ^ 1, (kc + 1) * 64)
        const unsigned short* Ar = smemU + cur * 12288;
        const unsigned short* Br = Ar + 4096;
#pragma unroll
        for (int kk = 0; kk < 2; ++kk) {
            short8 a[2], b[4];
#pragma unroll
            for (int i = 0; i < 2; ++i)
                a[i] = *(const short8*)&Ar[(wm * 32 + i * 16 + l15) * 64 +
                                           (((kk * 4 + quad) ^ sw) * 8)];
#pragma unroll
            for (int j = 0; j < 4; ++j)
                b[j] = *(const short8*)&Br[(wn * 64 + j * 16 + l15) * 64 +
                                           (((kk * 4 + quad) ^ sw) * 8)];
#pragma unroll
            for (int i = 0; i < 2; ++i)
#pragma unroll
                for (int j = 0; j < 4; ++j)
                    acc[i][j] = __builtin_amdgcn_mfma_f32_16x16x32_bf16(
                        a[i], b[j], acc[i][j], 0, 0, 0);
        }
        __syncthreads();
        cur ^= 1;
    }
#undef MSTAGE

    // epilogue: C/D layout col=lane&15, row=quad*4+reg
#pragma unroll
    for (int i = 0; i < 2; ++i) {
#pragma unroll
        for (int reg = 0; reg < 4; ++reg) {
            int mrow = m0 + wm * 32 + i * 16 + quad * 4 + reg;
#pragma unroll
            for (int j = 0; j < 4; ++j) {
                int ncol = n0 + wn * 64 + j * 16 + l15;
                float h = acc[i][j][reg];
                if (GELU) {
                    float g = 0.5f * h * (1.f + erff(h * 0.70710678118654752f));
                    unsigned short hb = f2bf_rn(g);
                    unsigned short lb = f2bf_rn(g - bf2f(hb));
                    size_t base = (size_t)mrow * 768;
                    Hs[base + ncol] = hb;
                    Hs[base + 256 + ncol] = lb;
                    Hs[base + 512 + ncol] = hb;
                } else {
                    C_t[(size_t)mrow * 8192 + ncol] = h;
                }
            }
        }
    }
}

// ---------------------------------------------------------------------------
// buildB: C_t [256][8192] -> Bhi/Blo [KCB][256]; csq, sC, sCl; per-128-tile
// maxima of sC/sCl; global maxima into accums[3]/[4]; per-dim sums atomically
// into partialC[256].
// ---------------------------------------------------------------------------
__global__ void k_buildB(const float* __restrict__ C_t,
                         unsigned short* __restrict__ Bhi,
                         unsigned short* __restrict__ Blo,
                         float* __restrict__ csq,
                         float* __restrict__ sC, float* __restrict__ sCl,
                         unsigned* __restrict__ tileMaxC, unsigned* __restrict__ tileMaxCl,
                         float* __restrict__ accums, float* __restrict__ partialC) {
    __shared__ ushort2 tile[64][65];
    __shared__ float kacc[64];
    __shared__ float lacc[64];
    __shared__ float pc[256];
    int t = threadIdx.x;
    int k0 = blockIdx.x * 64;
    if (t < 64) { kacc[t] = 0.f; lacc[t] = 0.f; }
    pc[t] = 0.f;
    __syncthreads();
    int nn_r = t & 63, dg = t >> 6;
    float a1 = 0.f, a2 = 0.f;
    for (int dc = 0; dc < 256; dc += 64) {
        for (int r = 0; r < 16; ++r) {
            int dd = r * 4 + dg;
            float v = C_t[(size_t)(dc + dd) * KCB + k0 + nn_r];
            unsigned short hb = f2bf_rn(v);
            float hf = bf2f(hb);
            unsigned short lb = f2bf_rn(v - hf);
            float lf = bf2f(lb);
            tile[dd][nn_r] = make_ushort2(hb, lb);
            a1 += v * v;
            a2 += lf * lf;
        }
        __syncthreads();
        int kk = t & 63, ng = t >> 6;
        float dimsum = 0.f;
        for (int i2 = 0; i2 < 16; ++i2) {
            int nn = ng + i2 * 4;
            ushort2 hl = tile[kk][nn];
            size_t base = (size_t)(k0 + nn) * 256;
            Bhi[base + dc + kk] = hl.x;
            Blo[base + dc + kk] = hl.y;
            dimsum += bf2f(hl.x) + bf2f(hl.y);
        }
        atomicAdd(&pc[dc + kk], dimsum);
        __syncthreads();
    }
    atomicAdd(&kacc[nn_r], a1);
    atomicAdd(&lacc[nn_r], a2);
    __syncthreads();
    if (t < 64) {
        float c2 = kacc[t], l2 = lacc[t];
        float sc = sqrtf(c2), sl = sqrtf(l2);
        csq[k0 + t] = c2;
        sC[k0 + t] = sc;
        sCl[k0 + t] = sl;
        int tl = blockIdx.x >> 1;
        atomicMax(&tileMaxC[tl], __float_as_uint(sc));
        atomicMax(&tileMaxCl[tl], __float_as_uint(sl));
        atomicMax((unsigned*)&accums[3], __float_as_uint(c2));
        atomicMax((unsigned*)&accums[4], __float_as_uint(l2));
    }
    atomicAdd(&partialC[t], pc[t]);
}

// ---------------------------------------------------------------------------
// Phase-1: d_hi GEMM, BM=256 x BN=256, 512 threads (8 waves), BK=64, 4 kc.
// R1-verbatim structure (137 us measured): 2 x 64 KB LDS dbuf, stage(kc+1)
// issued BEFORE the compute of kc, one __syncthreads per kc. Single 2048-
// block dispatch (block-scheduling serialization populates packed[] for
// later blocks -> tight thresholds; splitting by codebook broke this, R6).
// Value-only row-min; slim 2-pass epilogue + LDS-staged candidate appends.
// ---------------------------------------------------------------------------
__global__ __launch_bounds__(512, 2) void k_dist_hi(const unsigned short* __restrict__ A,
                                                    const unsigned short* __restrict__ B,
                                                    const float* __restrict__ zsq,
                                                    const float* __restrict__ csq,
                                                    const float* __restrict__ sA,
                                                    const float* __restrict__ sB,
                                                    const unsigned* __restrict__ tileMaxC,
                                                    const unsigned* __restrict__ tileMaxCl,
                                                    unsigned long long* __restrict__ packed,
                                                    float* __restrict__ accums,
                                                    unsigned long long* __restrict__ cand) {
    __shared__ __align__(16) char smem[131072];
    float* sbd     = (float*)smem;                   // [2][256]  0..2048
    float* gprev_s = (float*)(smem + 2048);          // [256]
    float* thr     = (float*)(smem + 3072);          // [256]
    unsigned* scnt  = (unsigned*)(smem + 4096);
    unsigned* sbase = (unsigned*)(smem + 4100);
    unsigned long long* scand = (unsigned long long*)(smem + 4112); // [SCAP]

    int t = threadIdx.x;
    int lane = t & 63;
    int w = t >> 6;                 // 0..7
    int wm = w >> 1, wn = w & 1;    // wm 0..3 (64 rows each), wn 0..1 (128 cols each)
    int m0 = blockIdx.x * 256;
    int n0 = blockIdx.y * 256;

    int rA0 = w * 8 + (lane >> 3);  // 0..63
    int ch_l = lane & 7;
    int ch_g = ch_l ^ (lane >> 3);
    const unsigned short* gA = A + (size_t)(m0 + rA0) * 256 + ch_g * 8;
    const unsigned short* gB = B + (size_t)(n0 + rA0) * 256 + ch_g * 8;
    unsigned short* smemU = (unsigned short*)smem;
    unsigned short* lA = smemU + rA0 * 64 + ch_l * 8;           // within buf0 A
    unsigned short* lB = smemU + 16384 + rA0 * 64 + ch_l * 8;   // within buf0 B

    int l15 = lane & 15;
    int quad = lane >> 4;
    int sw = l15 & 7;

    float M1 = sqrtf(accums[3]);
    float M2 = sqrtf(accums[4]);
    float msC  = fmaxf(__uint_as_float(tileMaxC[2 * blockIdx.y]),
                       __uint_as_float(tileMaxC[2 * blockIdx.y + 1]));
    float msCl = fmaxf(__uint_as_float(tileMaxCl[2 * blockIdx.y]),
                       __uint_as_float(tileMaxCl[2 * blockIdx.y + 1]));
    float cv[8];
    int cols[8];
#pragma unroll
    for (int j = 0; j < 8; ++j) {
        int cloc = wn * 128 + j * 16 + l15;
        cols[j] = n0 + cloc;
        cv[j] = csq[cols[j]];
    }

    f32x4 acc[4][8];
#pragma unroll
    for (int i = 0; i < 4; ++i)
#pragma unroll
        for (int j = 0; j < 8; ++j)
            acc[i][j] = f32x4{0.f, 0.f, 0.f, 0.f};

#define STAGE(B_, KO)                                                       \
    {                                                                       \
        int off_ = (B_) * 32768;                                            \
        _Pragma("unroll")                                                   \
        for (int i_ = 0; i_ < 4; ++i_)                                      \
            gl2lds16(gA + (size_t)(64 * i_) * 256 + (KO),                   \
                     lA + off_ + 64 * i_ * 64);                             \
        _Pragma("unroll")                                                   \
        for (int i_ = 0; i_ < 4; ++i_)                                      \
            gl2lds16(gB + (size_t)(64 * i_) * 256 + (KO),                   \
                     lB + off_ + 64 * i_ * 64);                             \
    }

    STAGE(0, 0)
    __syncthreads();   // kc=0 tile landed

    int cur = 0;
    for (int kc = 0; kc < 4; ++kc) {
        if (kc < 3) STAGE(cur ^ 1, (kc + 1) * 64)
        const unsigned short* Ar = smemU + cur * 32768;
        const unsigned short* Br = Ar + 16384;
#pragma unroll
        for (int kk = 0; kk < 2; ++kk) {
            short8 a[4], b[8];
#pragma unroll
            for (int i = 0; i < 4; ++i)
                a[i] = *(const short8*)&Ar[(wm * 64 + i * 16 + l15) * 64 +
                                            (((kk * 4 + quad) ^ sw) * 8)];
#pragma unroll
            for (int j = 0; j < 8; ++j)
                b[j] = *(const short8*)&Br[(wn * 128 + j * 16 + l15) * 64 +
                                            (((kk * 4 + quad) ^ sw) * 8)];
#pragma unroll
            for (int i = 0; i < 4; ++i)
#pragma unroll
                for (int j = 0; j < 8; ++j)
                    acc[i][j] = __builtin_amdgcn_mfma_f32_16x16x32_bf16(a[i], b[j], acc[i][j], 0, 0, 0);
        }
        __syncthreads();
        cur ^= 1;
    }
#undef STAGE

    // ---- pass 1: transform in place + value-only per-row min
    if (t == 0) *scnt = 0;
    if (t < 256) {
        const unsigned* hp = (const unsigned*)&packed[m0 + t];
        gprev_s[t] = __uint_as_float(__atomic_load_n(hp + 1, __ATOMIC_RELAXED));
    }
#pragma unroll
    for (int i = 0; i < 4; ++i) {
#pragma unroll
        for (int reg = 0; reg < 4; ++reg) {
            int rloc = wm * 64 + i * 16 + quad * 4 + reg;
            float zs = zsq[m0 + rloc];
            float bd = 3.4e38f;
#pragma unroll
            for (int j = 0; j < 8; ++j) {
                float d = (zs + cv[j]) - 2.0f * acc[i][j][reg];
                acc[i][j][reg] = d;
                bd = fminf(bd, d);
            }
#pragma unroll
            for (int off = 1; off < 16; off <<= 1)
                bd = fminf(bd, __shfl_xor(bd, off, 64));
            if (l15 == 0) sbd[wn * 256 + rloc] = bd;
        }
    }
    __syncthreads();
    if (t < 256) {
        float bd = fminf(sbd[t], sbd[256 + t]);
        atomicMin(&packed[m0 + t], (unsigned long long)__float_as_uint(bd) << 32);
        float g = fminf(bd, gprev_s[t]);
        thr[t] = g + 1e-3f + sA[m0 + t] * (M1 + msC) + sB[m0 + t] * (M2 + msCl);
    }
    __syncthreads();
    // ---- pass 2: 1-compare filter + staged appends
    unsigned* cnt = (unsigned*)&accums[2];
#pragma unroll
    for (int i = 0; i < 4; ++i) {
#pragma unroll
        for (int reg = 0; reg < 4; ++reg) {
            int rloc = wm * 64 + i * 16 + quad * 4 + reg;
            float tr = thr[rloc];
            bool p[8];
            bool any = false;
#pragma unroll
            for (int j = 0; j < 8; ++j) {
                p[j] = acc[i][j][reg] <= tr;
                any |= p[j];
            }
            if (__ballot(any)) {
                unsigned rbits = (unsigned)((m0 + rloc) << 13);
#pragma unroll
                for (int j = 0; j < 8; ++j) {
                    if (p[j]) {
                        unsigned long long entry =
                            ((unsigned long long)__float_as_uint(acc[i][j][reg]) << 32) |
                            (rbits | (unsigned)cols[j]);
                        unsigned pos = atomicAdd(scnt, 1u);
                        if (pos < SCAP) scand[pos] = entry;
                        else {
                            unsigned gp2 = atomicAdd(cnt, 1u);
                            if (gp2 < CAP) cand[gp2] = entry;
                        }
                    }
                }
            }
        }
    }
    __syncthreads();
    if (t == 0) {
        unsigned m = *scnt;
        if (m > SCAP) m = SCAP;
        *scnt = m;
        *sbase = atomicAdd(cnt, m);
    }
    __syncthreads();
    {
        unsigned m = *scnt, b0 = *sbase;
        for (unsigned u = t; u < m; u += 512)
            if (b0 + u < CAP) cand[b0 + u] = scand[u];
    }
}

// ---------------------------------------------------------------------------
// Phase-2: two-phase rescore (lane-parallel prefilter, one candidate per
// THREAD; survivors ballot-compacted to an LDS queue; block's 4 waves
// cooperatively run the exact 64-lane rescore). Same math, lex atomicMin.
// ---------------------------------------------------------------------------
__global__ __launch_bounds__(256) void k_rescore(const unsigned long long* __restrict__ cand,
                                                 const unsigned short* __restrict__ Ahi,
                                                 const unsigned short* __restrict__ Alo,
                                                 const unsigned short* __restrict__ Bhi,
                                                 const unsigned short* __restrict__ Blo,
                                                 const float* __restrict__ zsq,
                                                 const float* __restrict__ csq,
                                                 const float* __restrict__ sA,
                                                 const float* __restrict__ sB,
                                                 const float* __restrict__ sC,
                                                 const float* __restrict__ sCl,
                                                 const unsigned long long* __restrict__ packed,
                                                 unsigned long long* __restrict__ packed2,
                                                 const float* __restrict__ accums) {
    __shared__ unsigned long long q[256];
    __shared__ unsigned qn;
    unsigned total = *(const unsigned*)&accums[2];
    if (total > CAP) total = CAP;
    float M1 = sqrtf(accums[3]);
    float M2 = sqrtf(accums[4]);
    int t = threadIdx.x;
    int lane = t & 63;
    int w = t >> 6;
    unsigned per = (total + gridDim.x - 1) / gridDim.x;
    unsigned e0 = blockIdx.x * per;
    unsigned e1 = e0 + per;
    if (e1 > total) e1 = total;
    for (unsigned base = e0; base < e1; base += 256) {
        if (t == 0) qn = 0;
        __syncthreads();
        unsigned e = base + (unsigned)t;
        bool pass = false;
        unsigned long long ent = 0;
        if (e < e1) {
            ent = cand[e];
            float dhi = __uint_as_float((unsigned)(ent >> 32));
            unsigned nk = (unsigned)ent;
            int n = (nk >> 13) & 16383;
            int k = nk & 8191;
            float g = __uint_as_float((unsigned)(packed[n] >> 32));
            float marg = g + 1e-3f + sA[n] * (M1 + sC[k]) + sB[n] * (M2 + sCl[k]);
            pass = (dhi <= marg);
        }
        unsigned long long mask = __ballot(pass);
        if (mask) {
            unsigned cw = (unsigned)__popcll(mask);
            unsigned wbase = 0;
            if (lane == 0) wbase = atomicAdd(&qn, cw);
            wbase = __shfl(wbase, 0, 64);
            if (pass) {
                unsigned pos = wbase +
                    (unsigned)__popcll(mask & ((1ull << lane) - 1ull));
                q[pos] = ent;
            }
        }
        __syncthreads();
        unsigned m = qn;
        for (unsigned i = (unsigned)w; i < m; i += 4) {
            unsigned long long e2 = q[i];
            unsigned nk = (unsigned)e2;
            int n = (nk >> 13) & 16383;
            int k = nk & 8191;
            ushort4 zh = *((const ushort4*)(Ahi + (size_t)n * 256) + lane);
            ushort4 zl = *((const ushort4*)(Alo + (size_t)n * 256) + lane);
            ushort4 ch = *((const ushort4*)(Bhi + (size_t)k * 256) + lane);
            ushort4 cl = *((const ushort4*)(Blo + (size_t)k * 256) + lane);
            float s = (bf2f(zh.x) + bf2f(zl.x)) * (bf2f(ch.x) + bf2f(cl.x))
                    + (bf2f(zh.y) + bf2f(zl.y)) * (bf2f(ch.y) + bf2f(cl.y))
                    + (bf2f(zh.z) + bf2f(zl.z)) * (bf2f(ch.z) + bf2f(cl.z))
                    + (bf2f(zh.w) + bf2f(zl.w)) * (bf2f(ch.w) + bf2f(cl.w));
#pragma unroll
            for (int off = 1; off < 64; off <<= 1)
                s += __shfl_xor(s, off, 64);
            if (lane == 0) {
                float dd = (zsq[n] + csq[k]) - 2.0f * s;
                unsigned long long p =
                    ((unsigned long long)__float_as_uint(dd) << 32) | (unsigned)k;
                atomicMin(&packed2[n], p);
            }
        }
        __syncthreads();
    }
}

// ---------------------------------------------------------------------------
// zqloss (+fused unpack): reads packed2 directly for code indices, gathers
// codebook rows, writes out, accumulates VQ loss. Counts histogram spread
// evenly: each of the 512 blocks histograms 32 tokens.
// ---------------------------------------------------------------------------
__global__ void k_zqloss(const float* __restrict__ z, const float* __restrict__ C_t,
                         const unsigned long long* __restrict__ packed2,
                         float* __restrict__ out, float* __restrict__ loss_sum,
                         int* __restrict__ counts) {
    __shared__ float red[256];
    int bid = blockIdx.x;
    int b = bid >> 8;
    int d = bid & 255;
    int t = threadIdx.x;
    if (t < 32) {
        int kk = (int)(unsigned)packed2[bid * 32 + t] & 8191;
        atomicAdd(&counts[kk], 1);
    }
    const float* crow = C_t + (size_t)d * KCB;
    const unsigned long long* pb = packed2 + (size_t)b * THW;
    size_t base = ((size_t)(b * DIM + d)) * THW;
    float lsum = 0.f;
    for (int it = 0; it < 8; ++it) {
        int thw = it * 1024 + t * 4;
        ulonglong2 p01 = *(const ulonglong2*)&pb[thw];
        ulonglong2 p23 = *(const ulonglong2*)&pb[thw + 2];
        int i0 = (int)(unsigned)p01.x & 8191;
        int i1 = (int)(unsigned)p01.y & 8191;
        int i2 = (int)(unsigned)p23.x & 8191;
        int i3 = (int)(unsigned)p23.y & 8191;
        float4 zz = *(const float4*)&z[base + thw];
        float4 v;
        v.x = crow[i0]; v.y = crow[i1]; v.z = crow[i2]; v.w = crow[i3];
        *(float4*)&out[base + thw] = v;
        float d0 = v.x - zz.x, d1 = v.y - zz.y, d2 = v.z - zz.z, d3 = v.w - zz.w;
        lsum += d0 * d0 + d1 * d1 + d2 * d2 + d3 * d3;
    }
    red[t] = lsum;
    __syncthreads();
    for (int s = 128; s > 0; s >>= 1) {
        if (t < s) red[t] += red[t + s];
        __syncthreads();
    }
    if (t == 0) atomicAdd(loss_sum, red[0]);
}

// ---------------------------------------------------------------------------
// Final scalars: loss, perplexity, closed-form mean_distance.
// partialZ/partialC are already fully reduced [256] arrays.
// ---------------------------------------------------------------------------
__global__ void k_scalars(const int* __restrict__ counts,
                          const float* __restrict__ accums,
                          const float* __restrict__ zsq, const float* __restrict__ csq,
                          const float* __restrict__ partialZ,
                          const float* __restrict__ partialC,
                          float* __restrict__ out_tail) {
    __shared__ double redd[256];
    __shared__ float redf[256];
    int t = threadIdx.x;
    double szsq = 0.0, scsq = 0.0;
    for (int n = t; n < NTOK; n += 256) szsq += (double)zsq[n];
    for (int k = t; k < KCB; k += 256) scsq += (double)csq[k];
    float SZ = partialZ[t];
    float SC = partialC[t];
    double total = 8192.0 * szsq + 16384.0 * scsq - 2.0 * (double)SZ * (double)SC;
    redd[t] = total;
    float s = 0.f;
    for (int k = t; k < KCB; k += 256) {
        float e = (float)counts[k] * (1.0f / 16384.0f);
        s += e * logf(e + 1e-10f);
    }
    redf[t] = s;
    __syncthreads();
    for (int st = 128; st > 0; st >>= 1) {
        if (t < st) { redd[t] += redd[t + st]; redf[t] += redf[t + st]; }
        __syncthreads();
    }
    if (t == 0) {
        out_tail[0] = 1.25f * accums[1] / 4194304.0f;
        out_tail[1] = expf(-redf[0]);
        out_tail[2] = (float)(redd[0] / (16384.0 * 8192.0));
    }
}

// ---------------------------------------------------------------------------
extern "C" void kernel_launch(void* const* d_in, const int* in_sizes, int n_in,
                              void* d_out, int out_size, void* d_ws, size_t ws_size,
                              hipStream_t stream) {
    const float* z     = (const float*)d_in[0];   // [2][256][8192]
    const float* emb_w = (const float*)d_in[1];   // [8192][256]
    const float* w1    = (const float*)d_in[2];   // [256][256]
    const float* w2    = (const float*)d_in[3];   // [256][256]
    float* out = (float*)d_out;

    char* w = (char*)d_ws;
    unsigned short* Ahi = (unsigned short*)(w + 0);          //  8,388,608
    unsigned short* Alo = (unsigned short*)(w + 8388608);    //  8,388,608
    unsigned short* Ebf = (unsigned short*)(w + 16777216);   // 12,582,912 (E'; C_t aliases after mlp1)
    unsigned short* Bhi = (unsigned short*)(w + 29360128);   //  4,194,304
    unsigned short* Blo = (unsigned short*)(w + 33554432);   //  4,194,304
    unsigned short* W1s = (unsigned short*)(w + 37748736);   //    393,216
    unsigned short* W2s = (unsigned short*)(w + 38141952);   //    393,216
    float* zsq   = (float*)(w + 38535168);   // 65,536
    float* sA    = (float*)(w + 38666240);   // 65,536
    float* sB    = (float*)(w + 38731776);   // 65,536
    float* csq   = (float*)(w + 38797312);   // 32,768
    float* sC    = (float*)(w + 38862848);   // 32,768
    float* sCl   = (float*)(w + 38895616);   // 32,768
    unsigned long long* packed  = (unsigned long long*)(w + 38928384); // 131,072
    unsigned long long* packed2 = (unsigned long long*)(w + 39059456); // 131,072
    int*   counts = (int*)(w + 39256064);    // 32,768
    float* partialZ = (float*)(w + 39288832); // [256] pre-reduced
    float* partialC = (float*)(w + 39550976); // [256] pre-reduced
    unsigned* tileMaxC  = (unsigned*)(w + 39682048); // 256
    unsigned* tileMaxCl = (unsigned*)(w + 39682304); // 256
    float* accums = (float*)(w + 39682560);  // [1]loss [2]cnt [3]csqmax [4]closqmax

    float* C_t = (float*)Ebf;                        // alias: E' dead after mlp1
    unsigned short* Hs = (unsigned short*)d_out;     // Hs then cand share d_out
    unsigned long long* cand = (unsigned long long*)d_out;

    // prep: splitW + buildA + buildE fused (independent work, one launch;
    // also does all housekeeping zeroing and packed/packed2 init)
    k_prep<<<2816, 256, 0, stream>>>(w1, w2, W1s, W2s, counts,
                                     tileMaxC, tileMaxCl, accums, partialZ, partialC,
                                     z, Ahi, Alo, zsq, sA, sB, packed, packed2,
                                     emb_w, Ebf);

    // MLP: Hs[k][768] = split(gelu(E' x W1s^T))  (codes on the M side)
    k_mlp<1><<<dim3(2, 128), 256, 0, stream>>>(Ebf, W1s, Hs, nullptr);
    // C_t[d][8192] = W2s x Hs^T
    k_mlp<0><<<dim3(64, 4), 256, 0, stream>>>(W2s, Hs, nullptr, C_t);

    k_buildB<<<KCB / 64, 256, 0, stream>>>(C_t, Bhi, Blo, csq, sC, sCl,
                                           tileMaxC, tileMaxCl, accums, partialC);

    // Phase-1: d_hi GEMM (256x256 tiles, R1 structure, single dispatch)
    k_dist_hi<<<dim3(NTOK / 256, KCB / 256), 512, 0, stream>>>(
        Ahi, Bhi, zsq, csq, sA, sB, tileMaxC, tileMaxCl, packed, accums, cand);

    // Phase-2: two-phase rescore (lane-parallel prefilter + wave rescore)
    k_rescore<<<2048, 256, 0, stream>>>(cand, Ahi, Alo, Bhi, Blo, zsq, csq,
                                        sA, sB, sC, sCl, packed, packed2, accums);

    // zqloss (+fused histogram, evenly spread)
    k_zqloss<<<BATCH * DIM, 256, 0, stream>>>(z, C_t, packed2, out, accums + 1, counts);
    k_scalars<<<1, 256, 0, stream>>>(counts, accums, zsq, csq, partialZ, partialC, out + OUTQ);
}

// Round 10
// 340.022 us; speedup vs baseline: 1.3057x; 1.0460x over previous
//
#include <hip/hip_runtime.h>
#include <math.h>

// Problem constants (fixed by setup_inputs)
#define BATCH 2
#define DIM   256
#define THW   8192            // T*H*W = 8*32*32
#define NTOK  16384           // BATCH*THW
#define KCB   8192            // codebook size
#define OUTQ  4194304         // BATCH*DIM*THW
#define CAP   2000000         // candidate buffer entries (16 MB in d_out)
#define SCAP  5600            // per-block LDS candidate staging capacity

typedef short short8 __attribute__((ext_vector_type(8)));
typedef float f32x4 __attribute__((ext_vector_type(4)));

__device__ __forceinline__ unsigned short f2bf_rn(float v) {
    unsigned u = __float_as_uint(v);
    unsigned r = u + 0x7FFFu + ((u >> 16) & 1u);
    return (unsigned short)(r >> 16);
}
__device__ __forceinline__ float bf2f(unsigned short b) {
    return __uint_as_float((unsigned)b << 16);
}
__device__ __forceinline__ void gl2lds16(const unsigned short* g, unsigned short* l) {
    __builtin_amdgcn_global_load_lds(
        (const __attribute__((address_space(1))) void*)g,
        (__attribute__((address_space(3))) void*)l, 16, 0, 0);
}

// ---------------------------------------------------------------------------
// prep: one launch fusing three independent preprocessing kernels
//   bid 0..511    : splitW (w1/w2 -> W1s/W2s) + housekeeping zeroing
//   bid 512..1023 : buildA v2 (z -> Ahi/Alo, zsq/sA/sB, partialZ, packed
//                   init). v2: float4 z loads (16B/lane, was scalar 4B) and
//                   32 tokens/block over 512 blocks (2x TLP, half the
//                   per-thread serial load depth) -- buildA was latency-
//                   bound at 1 wave/SIMD with scalar loads (R9: prep 158us,
//                   occupancy 0.3%, VALUBusy 0.2% => issue/latency-bound).
//   bid 1024..3071: buildE (emb -> E' [8192][768]=[hi|lo|hi])
// ---------------------------------------------------------------------------
__global__ void k_prep(const float* __restrict__ w1, const float* __restrict__ w2,
                       unsigned short* __restrict__ W1s, unsigned short* __restrict__ W2s,
                       int* __restrict__ counts,
                       unsigned* __restrict__ tileMaxC, unsigned* __restrict__ tileMaxCl,
                       float* __restrict__ accums,
                       float* __restrict__ partialZ, float* __restrict__ partialC,
                       const float* __restrict__ z,
                       unsigned short* __restrict__ Ahi, unsigned short* __restrict__ Alo,
                       float* __restrict__ zsq, float* __restrict__ sA, float* __restrict__ sB,
                       unsigned long long* __restrict__ packed,
                       unsigned long long* __restrict__ packed2,
                       const float* __restrict__ emb, unsigned short* __restrict__ E) {
    __shared__ ushort2 tile[64][33];   // [dim][token], 2-way-max banks (free)
    __shared__ float zacc[32];
    __shared__ float lacc[32];
    __shared__ float pz[256];
    int bid = blockIdx.x;
    int t = threadIdx.x;

    if (bid < 512) {
        // ---- splitW + housekeeping ----
        if (bid < 32) {
            counts[bid * 256 + t] = 0;
        } else if (bid == 32) {
            if (t < 64) { tileMaxC[t] = 0u; tileMaxCl[t] = 0u; }
            if (t >= 64 && t < 72) accums[t - 64] = 0.f;
        } else if (bid == 33) {
            partialZ[t] = 0.f;
        } else if (bid == 34) {
            partialC[t] = 0.f;
        }
        int row = bid & 255;
        const float* src = (bid >> 8) ? w2 : w1;
        unsigned short* dst = ((bid >> 8) ? W2s : W1s) + (size_t)row * 768;
        float v = src[row * 256 + t];
        unsigned short hb = f2bf_rn(v);
        unsigned short lb = f2bf_rn(v - bf2f(hb));
        dst[t] = hb;
        dst[256 + t] = hb;
        dst[512 + t] = lb;
        return;
    }
    if (bid >= 1024) {
        // ---- buildE ----
        int row = (bid - 1024) * 4 + (t >> 6);
        int e4 = (t & 63) * 4;
        float4 v = *(const float4*)&emb[(size_t)row * 256 + e4];
        ushort4 hi, lo;
        hi.x = f2bf_rn(v.x); lo.x = f2bf_rn(v.x - bf2f(hi.x));
        hi.y = f2bf_rn(v.y); lo.y = f2bf_rn(v.y - bf2f(hi.y));
        hi.z = f2bf_rn(v.z); lo.z = f2bf_rn(v.z - bf2f(hi.z));
        hi.w = f2bf_rn(v.w); lo.w = f2bf_rn(v.w - bf2f(hi.w));
        size_t base = (size_t)row * 768;
        *(ushort4*)&E[base + e4] = hi;
        *(ushort4*)&E[base + 256 + e4] = lo;
        *(ushort4*)&E[base + 512 + e4] = hi;
        return;
    }
    // ---- buildA v2: 32 tokens/block, float4 loads ----
    int n0 = (bid - 512) * 32;
    int b = n0 >> 13;
    int thw0 = n0 & 8191;
    if (t < 32) {
        zacc[t] = 0.f; lacc[t] = 0.f;
        packed[n0 + t] = ~0ull;
        packed2[n0 + t] = ~0ull;
    }
    pz[t] = 0.f;
    __syncthreads();
    int tok4 = (t & 7) * 4;        // token group (4 tokens via float4)
    int drow = t >> 3;             // 0..31 dim row within half-chunk
    float a1[4] = {0.f, 0.f, 0.f, 0.f};
    float a2[4] = {0.f, 0.f, 0.f, 0.f};
    for (int dc = 0; dc < 256; dc += 64) {
        // load phase: 2 iters x 32 rows x 32 tokens (float4 per thread)
        for (int r = 0; r < 2; ++r) {
            int dd = drow + r * 32;
            float4 v4 = *(const float4*)&z[((size_t)(b * 256 + dc + dd)) * 8192 +
                                           thw0 + tok4];
            float ve[4];
            *(float4*)ve = v4;
#pragma unroll
            for (int e = 0; e < 4; ++e) {
                float v = ve[e];
                unsigned short hb = f2bf_rn(v);
                float hf = bf2f(hb);
                unsigned short lb = f2bf_rn(v - hf);
                float lf = bf2f(lb);
                tile[dd][tok4 + e] = make_ushort2(hb, lb);
                a1[e] += v * v;
                a2[e] += lf * lf;
            }
        }
        __syncthreads();
        // write-out phase (transpose): token-major Ahi/Alo rows
        int kk = t & 63, ng = t >> 6;
        float dimsum = 0.f;
        for (int i2 = 0; i2 < 8; ++i2) {
            int nn = ng + i2 * 4;                 // 0..31
            ushort2 hl = tile[kk][nn];
            size_t base = (size_t)(n0 + nn) * 256;
            Ahi[base + dc + kk] = hl.x;
            Alo[base + dc + kk] = hl.y;
            dimsum += bf2f(hl.x) + bf2f(hl.y);
        }
        atomicAdd(&pz[dc + kk], dimsum);
        __syncthreads();
    }
#pragma unroll
    for (int e = 0; e < 4; ++e) {
        atomicAdd(&zacc[tok4 + e], a1[e]);
        atomicAdd(&lacc[tok4 + e], a2[e]);
    }
    __syncthreads();
    if (t < 32) {
        zsq[n0 + t] = zacc[t];
        sA[n0 + t] = 2.1f * sqrtf(lacc[t]);
        sB[n0 + t] = 2.1f * sqrtf(zacc[t]);
    }
    atomicAdd(&partialZ[t], pz[t]);
}

// ---------------------------------------------------------------------------
// MLP GEMM on split-bf16 MFMA. v2: BM=64 x BN=128, BK=64, 12 kc, 256 thr
// (4 waves 2x2, wave tile 32x64, acc[2][4]). 256 blocks = full GPU;
// R1-style LDS double-buffer (stage(kc+1) before compute(kc), 1 barrier/kc).
// ---------------------------------------------------------------------------
template <int GELU>
__global__ __launch_bounds__(256) void k_mlp(const unsigned short* __restrict__ A,
                                             const unsigned short* __restrict__ B,
                                             unsigned short* __restrict__ Hs,
                                             float* __restrict__ C_t) {
    __shared__ __align__(16) char smem[49152];
    unsigned short* smemU = (unsigned short*)smem;
    // buf b at ushort offset b*12288: A [64][64] at +0, B [128][64] at +4096

    int t = threadIdx.x;
    int lane = t & 63;
    int w = t >> 6;
    int wm = w >> 1, wn = w & 1;        // wave tile 32(m) x 64(n)
    int m0 = blockIdx.y * 64;
    int n0 = blockIdx.x * 128;

    int rA0 = w * 8 + (lane >> 3);      // 0..31
    int ch_l = lane & 7;
    int ch_g = ch_l ^ (rA0 & 7);        // (rA0+32g)&7 == rA0&7
    const unsigned short* gA = A + (size_t)(m0 + rA0) * 768 + ch_g * 8;
    const unsigned short* gB = B + (size_t)(n0 + rA0) * 768 + ch_g * 8;
    int lds0 = rA0 * 64 + ch_l * 8;

    f32x4 acc[2][4];
#pragma unroll
    for (int i = 0; i < 2; ++i)
#pragma unroll
        for (int j = 0; j < 4; ++j)
            acc[i][j] = f32x4{0.f, 0.f, 0.f, 0.f};

#define MSTAGE(BUF, KO)                                                     \
    {                                                                       \
        unsigned short* ba_ = smemU + (BUF) * 12288;                        \
        gl2lds16(gA + (KO), ba_ + lds0);                                    \
        gl2lds16(gA + (KO) + (size_t)32 * 768, ba_ + 2048 + lds0);          \
        _Pragma("unroll")                                                   \
        for (int g_ = 0; g_ < 4; ++g_)                                      \
            gl2lds16(gB + (KO) + (size_t)(32 * g_) * 768,                   \
                     ba_ + 4096 + g_ * 2048 + lds0);                        \
    }

    MSTAGE(0, 0)
    __syncthreads();

    int l15 = lane & 15;
    int quad = lane >> 4;
    int sw = l15 & 7;
    int cur = 0;
    for (int kc = 0; kc < 12; ++kc) {
        if (kc < 11) MSTAGE(cur ^ 1, (kc + 1) * 64)
        const unsigned short* Ar = smemU + cur * 12288;
        const unsigned short* Br = Ar + 4096;
#pragma unroll
        for (int kk = 0; kk < 2; ++kk) {
            short8 a[2], b[4];
#pragma unroll
            for (int i = 0; i < 2; ++i)
                a[i] = *(const short8*)&Ar[(wm * 32 + i * 16 + l15) * 64 +
                                           (((kk * 4 + quad) ^ sw) * 8)];
#pragma unroll
            for (int j = 0; j < 4; ++j)
                b[j] = *(const short8*)&Br[(wn * 64 + j * 16 + l15) * 64 +
                                           (((kk * 4 + quad) ^ sw) * 8)];
#pragma unroll
            for (int i = 0; i < 2; ++i)
#pragma unroll
                for (int j = 0; j < 4; ++j)
                    acc[i][j] = __builtin_amdgcn_mfma_f32_16x16x32_bf16(
                        a[i], b[j], acc[i][j], 0, 0, 0);
        }
        __syncthreads();
        cur ^= 1;
    }
#undef MSTAGE

    // epilogue: C/D layout col=lane&15, row=quad*4+reg
#pragma unroll
    for (int i = 0; i < 2; ++i) {
#pragma unroll
        for (int reg = 0; reg < 4; ++reg) {
            int mrow = m0 + wm * 32 + i * 16 + quad * 4 + reg;
#pragma unroll
            for (int j = 0; j < 4; ++j) {
                int ncol = n0 + wn * 64 + j * 16 + l15;
                float h = acc[i][j][reg];
                if (GELU) {
                    float g = 0.5f * h * (1.f + erff(h * 0.70710678118654752f));
                    unsigned short hb = f2bf_rn(g);
                    unsigned short lb = f2bf_rn(g - bf2f(hb));
                    size_t base = (size_t)mrow * 768;
                    Hs[base + ncol] = hb;
                    Hs[base + 256 + ncol] = lb;
                    Hs[base + 512 + ncol] = hb;
                } else {
                    C_t[(size_t)mrow * 8192 + ncol] = h;
                }
            }
        }
    }
}

// ---------------------------------------------------------------------------
// buildB: C_t [256][8192] -> Bhi/Blo [KCB][256]; csq, sC, sCl; per-128-tile
// maxima of sC/sCl; global maxima into accums[3]/[4]; per-dim sums atomically
// into partialC[256].
// ---------------------------------------------------------------------------
__global__ void k_buildB(const float* __restrict__ C_t,
                         unsigned short* __restrict__ Bhi,
                         unsigned short* __restrict__ Blo,
                         float* __restrict__ csq,
                         float* __restrict__ sC, float* __restrict__ sCl,
                         unsigned* __restrict__ tileMaxC, unsigned* __restrict__ tileMaxCl,
                         float* __restrict__ accums, float* __restrict__ partialC) {
    __shared__ ushort2 tile[64][65];
    __shared__ float kacc[64];
    __shared__ float lacc[64];
    __shared__ float pc[256];
    int t = threadIdx.x;
    int k0 = blockIdx.x * 64;
    if (t < 64) { kacc[t] = 0.f; lacc[t] = 0.f; }
    pc[t] = 0.f;
    __syncthreads();
    int nn_r = t & 63, dg = t >> 6;
    float a1 = 0.f, a2 = 0.f;
    for (int dc = 0; dc < 256; dc += 64) {
        for (int r = 0; r < 16; ++r) {
            int dd = r * 4 + dg;
            float v = C_t[(size_t)(dc + dd) * KCB + k0 + nn_r];
            unsigned short hb = f2bf_rn(v);
            float hf = bf2f(hb);
            unsigned short lb = f2bf_rn(v - hf);
            float lf = bf2f(lb);
            tile[dd][nn_r] = make_ushort2(hb, lb);
            a1 += v * v;
            a2 += lf * lf;
        }
        __syncthreads();
        int kk = t & 63, ng = t >> 6;
        float dimsum = 0.f;
        for (int i2 = 0; i2 < 16; ++i2) {
            int nn = ng + i2 * 4;
            ushort2 hl = tile[kk][nn];
            size_t base = (size_t)(k0 + nn) * 256;
            Bhi[base + dc + kk] = hl.x;
            Blo[base + dc + kk] = hl.y;
            dimsum += bf2f(hl.x) + bf2f(hl.y);
        }
        atomicAdd(&pc[dc + kk], dimsum);
        __syncthreads();
    }
    atomicAdd(&kacc[nn_r], a1);
    atomicAdd(&lacc[nn_r], a2);
    __syncthreads();
    if (t < 64) {
        float c2 = kacc[t], l2 = lacc[t];
        float sc = sqrtf(c2), sl = sqrtf(l2);
        csq[k0 + t] = c2;
        sC[k0 + t] = sc;
        sCl[k0 + t] = sl;
        int tl = blockIdx.x >> 1;
        atomicMax(&tileMaxC[tl], __float_as_uint(sc));
        atomicMax(&tileMaxCl[tl], __float_as_uint(sl));
        atomicMax((unsigned*)&accums[3], __float_as_uint(c2));
        atomicMax((unsigned*)&accums[4], __float_as_uint(l2));
    }
    atomicAdd(&partialC[t], pc[t]);
}

// ---------------------------------------------------------------------------
// Phase-1: d_hi GEMM, BM=256 x BN=256, 512 threads (8 waves), BK=64, 4 kc.
// R1-verbatim structure (137 us measured): 2 x 64 KB LDS dbuf, stage(kc+1)
// issued BEFORE the compute of kc, one __syncthreads per kc. Single 2048-
// block dispatch (block-scheduling serialization populates packed[] for
// later blocks -> tight thresholds; splitting by codebook broke this, R6).
// Value-only row-min; slim 2-pass epilogue + LDS-staged candidate appends.
// ---------------------------------------------------------------------------
__global__ __launch_bounds__(512, 2) void k_dist_hi(const unsigned short* __restrict__ A,
                                                    const unsigned short* __restrict__ B,
                                                    const float* __restrict__ zsq,
                                                    const float* __restrict__ csq,
                                                    const float* __restrict__ sA,
                                                    const float* __restrict__ sB,
                                                    const unsigned* __restrict__ tileMaxC,
                                                    const unsigned* __restrict__ tileMaxCl,
                                                    unsigned long long* __restrict__ packed,
                                                    float* __restrict__ accums,
                                                    unsigned long long* __restrict__ cand) {
    __shared__ __align__(16) char smem[131072];
    float* sbd     = (float*)smem;                   // [2][256]  0..2048
    float* gprev_s = (float*)(smem + 2048);          // [256]
    float* thr     = (float*)(smem + 3072);          // [256]
    unsigned* scnt  = (unsigned*)(smem + 4096);
    unsigned* sbase = (unsigned*)(smem + 4100);
    unsigned long long* scand = (unsigned long long*)(smem + 4112); // [SCAP]

    int t = threadIdx.x;
    int lane = t & 63;
    int w = t >> 6;                 // 0..7
    int wm = w >> 1, wn = w & 1;    // wm 0..3 (64 rows each), wn 0..1 (128 cols each)
    int m0 = blockIdx.x * 256;
    int n0 = blockIdx.y * 256;

    int rA0 = w * 8 + (lane >> 3);  // 0..63
    int ch_l = lane & 7;
    int ch_g = ch_l ^ (lane >> 3);
    const unsigned short* gA = A + (size_t)(m0 + rA0) * 256 + ch_g * 8;
    const unsigned short* gB = B + (size_t)(n0 + rA0) * 256 + ch_g * 8;
    unsigned short* smemU = (unsigned short*)smem;
    unsigned short* lA = smemU + rA0 * 64 + ch_l * 8;           // within buf0 A
    unsigned short* lB = smemU + 16384 + rA0 * 64 + ch_l * 8;   // within buf0 B

    int l15 = lane & 15;
    int quad = lane >> 4;
    int sw = l15 & 7;

    float M1 = sqrtf(accums[3]);
    float M2 = sqrtf(accums[4]);
    float msC  = fmaxf(__uint_as_float(tileMaxC[2 * blockIdx.y]),
                       __uint_as_float(tileMaxC[2 * blockIdx.y + 1]));
    float msCl = fmaxf(__uint_as_float(tileMaxCl[2 * blockIdx.y]),
                       __uint_as_float(tileMaxCl[2 * blockIdx.y + 1]));
    float cv[8];
    int cols[8];
#pragma unroll
    for (int j = 0; j < 8; ++j) {
        int cloc = wn * 128 + j * 16 + l15;
        cols[j] = n0 + cloc;
        cv[j] = csq[cols[j]];
    }

    f32x4 acc[4][8];
#pragma unroll
    for (int i = 0; i < 4; ++i)
#pragma unroll
        for (int j = 0; j < 8; ++j)
            acc[i][j] = f32x4{0.f, 0.f, 0.f, 0.f};

#define STAGE(B_, KO)                                                       \
    {                                                                       \
        int off_ = (B_) * 32768;                                            \
        _Pragma("unroll")                                                   \
        for (int i_ = 0; i_ < 4; ++i_)                                      \
            gl2lds16(gA + (size_t)(64 * i_) * 256 + (KO),                   \
                     lA + off_ + 64 * i_ * 64);                             \
        _Pragma("unroll")                                                   \
        for (int i_ = 0; i_ < 4; ++i_)                                      \
            gl2lds16(gB + (size_t)(64 * i_) * 256 + (KO),                   \
                     lB + off_ + 64 * i_ * 64);                             \
    }

    STAGE(0, 0)
    __syncthreads();   // kc=0 tile landed

    int cur = 0;
    for (int kc = 0; kc < 4; ++kc) {
        if (kc < 3) STAGE(cur ^ 1, (kc + 1) * 64)
        const unsigned short* Ar = smemU + cur * 32768;
        const unsigned short* Br = Ar + 16384;
#pragma unroll
        for (int kk = 0; kk < 2; ++kk) {
            short8 a[4], b[8];
#pragma unroll
            for (int i = 0; i < 4; ++i)
                a[i] = *(const short8*)&Ar[(wm * 64 + i * 16 + l15) * 64 +
                                            (((kk * 4 + quad) ^ sw) * 8)];
#pragma unroll
            for (int j = 0; j < 8; ++j)
                b[j] = *(const short8*)&Br[(wn * 128 + j * 16 + l15) * 64 +
                                            (((kk * 4 + quad) ^ sw) * 8)];
#pragma unroll
            for (int i = 0; i < 4; ++i)
#pragma unroll
                for (int j = 0; j < 8; ++j)
                    acc[i][j] = __builtin_amdgcn_mfma_f32_16x16x32_bf16(a[i], b[j], acc[i][j], 0, 0, 0);
        }
        __syncthreads();
        cur ^= 1;
    }
#undef STAGE

    // ---- pass 1: transform in place + value-only per-row min
    if (t == 0) *scnt = 0;
    if (t < 256) {
        const unsigned* hp = (const unsigned*)&packed[m0 + t];
        gprev_s[t] = __uint_as_float(__atomic_load_n(hp + 1, __ATOMIC_RELAXED));
    }
#pragma unroll
    for (int i = 0; i < 4; ++i) {
#pragma unroll
        for (int reg = 0; reg < 4; ++reg) {
            int rloc = wm * 64 + i * 16 + quad * 4 + reg;
            float zs = zsq[m0 + rloc];
            float bd = 3.4e38f;
#pragma unroll
            for (int j = 0; j < 8; ++j) {
                float d = (zs + cv[j]) - 2.0f * acc[i][j][reg];
                acc[i][j][reg] = d;
                bd = fminf(bd, d);
            }
#pragma unroll
            for (int off = 1; off < 16; off <<= 1)
                bd = fminf(bd, __shfl_xor(bd, off, 64));
            if (l15 == 0) sbd[wn * 256 + rloc] = bd;
        }
    }
    __syncthreads();
    if (t < 256) {
        float bd = fminf(sbd[t], sbd[256 + t]);
        atomicMin(&packed[m0 + t], (unsigned long long)__float_as_uint(bd) << 32);
        float g = fminf(bd, gprev_s[t]);
        thr[t] = g + 1e-3f + sA[m0 + t] * (M1 + msC) + sB[m0 + t] * (M2 + msCl);
    }
    __syncthreads();
    // ---- pass 2: 1-compare filter + staged appends
    unsigned* cnt = (unsigned*)&accums[2];
#pragma unroll
    for (int i = 0; i < 4; ++i) {
#pragma unroll
        for (int reg = 0; reg < 4; ++reg) {
            int rloc = wm * 64 + i * 16 + quad * 4 + reg;
            float tr = thr[rloc];
            bool p[8];
            bool any = false;
#pragma unroll
            for (int j = 0; j < 8; ++j) {
                p[j] = acc[i][j][reg] <= tr;
                any |= p[j];
            }
            if (__ballot(any)) {
                unsigned rbits = (unsigned)((m0 + rloc) << 13);
#pragma unroll
                for (int j = 0; j < 8; ++j) {
                    if (p[j]) {
                        unsigned long long entry =
                            ((unsigned long long)__float_as_uint(acc[i][j][reg]) << 32) |
                            (rbits | (unsigned)cols[j]);
                        unsigned pos = atomicAdd(scnt, 1u);
                        if (pos < SCAP) scand[pos] = entry;
                        else {
                            unsigned gp2 = atomicAdd(cnt, 1u);
                            if (gp2 < CAP) cand[gp2] = entry;
                        }
                    }
                }
            }
        }
    }
    __syncthreads();
    if (t == 0) {
        unsigned m = *scnt;
        if (m > SCAP) m = SCAP;
        *scnt = m;
        *sbase = atomicAdd(cnt, m);
    }
    __syncthreads();
    {
        unsigned m = *scnt, b0 = *sbase;
        for (unsigned u = t; u < m; u += 512)
            if (b0 + u < CAP) cand[b0 + u] = scand[u];
    }
}

// ---------------------------------------------------------------------------
// Phase-2: two-phase rescore (lane-parallel prefilter, one candidate per
// THREAD; survivors ballot-compacted to an LDS queue; block's 4 waves
// cooperatively run the exact 64-lane rescore). Same math, lex atomicMin.
// ---------------------------------------------------------------------------
__global__ __launch_bounds__(256) void k_rescore(const unsigned long long* __restrict__ cand,
                                                 const unsigned short* __restrict__ Ahi,
                                                 const unsigned short* __restrict__ Alo,
                                                 const unsigned short* __restrict__ Bhi,
                                                 const unsigned short* __restrict__ Blo,
                                                 const float* __restrict__ zsq,
                                                 const float* __restrict__ csq,
                                                 const float* __restrict__ sA,
                                                 const float* __restrict__ sB,
                                                 const float* __restrict__ sC,
                                                 const float* __restrict__ sCl,
                                                 const unsigned long long* __restrict__ packed,
                                                 unsigned long long* __restrict__ packed2,
                                                 const float* __restrict__ accums) {
    __shared__ unsigned long long q[256];
    __shared__ unsigned qn;
    unsigned total = *(const unsigned*)&accums[2];
    if (total > CAP) total = CAP;
    float M1 = sqrtf(accums[3]);
    float M2 = sqrtf(accums[4]);
    int t = threadIdx.x;
    int lane = t & 63;
    int w = t >> 6;
    unsigned per = (total + gridDim.x - 1) / gridDim.x;
    unsigned e0 = blockIdx.x * per;
    unsigned e1 = e0 + per;
    if (e1 > total) e1 = total;
    for (unsigned base = e0; base < e1; base += 256) {
        if (t == 0) qn = 0;
        __syncthreads();
        unsigned e = base + (unsigned)t;
        bool pass = false;
        unsigned long long ent = 0;
        if (e < e1) {
            ent = cand[e];
            float dhi = __uint_as_float((unsigned)(ent >> 32));
            unsigned nk = (unsigned)ent;
            int n = (nk >> 13) & 16383;
            int k = nk & 8191;
            float g = __uint_as_float((unsigned)(packed[n] >> 32));
            float marg = g + 1e-3f + sA[n] * (M1 + sC[k]) + sB[n] * (M2 + sCl[k]);
            pass = (dhi <= marg);
        }
        unsigned long long mask = __ballot(pass);
        if (mask) {
            unsigned cw = (unsigned)__popcll(mask);
            unsigned wbase = 0;
            if (lane == 0) wbase = atomicAdd(&qn, cw);
            wbase = __shfl(wbase, 0, 64);
            if (pass) {
                unsigned pos = wbase +
                    (unsigned)__popcll(mask & ((1ull << lane) - 1ull));
                q[pos] = ent;
            }
        }
        __syncthreads();
        unsigned m = qn;
        for (unsigned i = (unsigned)w; i < m; i += 4) {
            unsigned long long e2 = q[i];
            unsigned nk = (unsigned)e2;
            int n = (nk >> 13) & 16383;
            int k = nk & 8191;
            ushort4 zh = *((const ushort4*)(Ahi + (size_t)n * 256) + lane);
            ushort4 zl = *((const ushort4*)(Alo + (size_t)n * 256) + lane);
            ushort4 ch = *((const ushort4*)(Bhi + (size_t)k * 256) + lane);
            ushort4 cl = *((const ushort4*)(Blo + (size_t)k * 256) + lane);
            float s = (bf2f(zh.x) + bf2f(zl.x)) * (bf2f(ch.x) + bf2f(cl.x))
                    + (bf2f(zh.y) + bf2f(zl.y)) * (bf2f(ch.y) + bf2f(cl.y))
                    + (bf2f(zh.z) + bf2f(zl.z)) * (bf2f(ch.z) + bf2f(cl.z))
                    + (bf2f(zh.w) + bf2f(zl.w)) * (bf2f(ch.w) + bf2f(cl.w));
#pragma unroll
            for (int off = 1; off < 64; off <<= 1)
                s += __shfl_xor(s, off, 64);
            if (lane == 0) {
                float dd = (zsq[n] + csq[k]) - 2.0f * s;
                unsigned long long p =
                    ((unsigned long long)__float_as_uint(dd) << 32) | (unsigned)k;
                atomicMin(&packed2[n], p);
            }
        }
        __syncthreads();
    }
}

// ---------------------------------------------------------------------------
// zqloss (+fused unpack): reads packed2 directly for code indices, gathers
// codebook rows, writes out, accumulates VQ loss. Counts histogram spread
// evenly: each of the 512 blocks histograms 32 tokens.
// ---------------------------------------------------------------------------
__global__ void k_zqloss(const float* __restrict__ z, const float* __restrict__ C_t,
                         const unsigned long long* __restrict__ packed2,
                         float* __restrict__ out, float* __restrict__ loss_sum,
                         int* __restrict__ counts) {
    __shared__ float red[256];
    int bid = blockIdx.x;
    int b = bid >> 8;
    int d = bid & 255;
    int t = threadIdx.x;
    if (t < 32) {
        int kk = (int)(unsigned)packed2[bid * 32 + t] & 8191;
        atomicAdd(&counts[kk], 1);
    }
    const float* crow = C_t + (size_t)d * KCB;
    const unsigned long long* pb = packed2 + (size_t)b * THW;
    size_t base = ((size_t)(b * DIM + d)) * THW;
    float lsum = 0.f;
    for (int it = 0; it < 8; ++it) {
        int thw = it * 1024 + t * 4;
        ulonglong2 p01 = *(const ulonglong2*)&pb[thw];
        ulonglong2 p23 = *(const ulonglong2*)&pb[thw + 2];
        int i0 = (int)(unsigned)p01.x & 8191;
        int i1 = (int)(unsigned)p01.y & 8191;
        int i2 = (int)(unsigned)p23.x & 8191;
        int i3 = (int)(unsigned)p23.y & 8191;
        float4 zz = *(const float4*)&z[base + thw];
        float4 v;
        v.x = crow[i0]; v.y = crow[i1]; v.z = crow[i2]; v.w = crow[i3];
        *(float4*)&out[base + thw] = v;
        float d0 = v.x - zz.x, d1 = v.y - zz.y, d2 = v.z - zz.z, d3 = v.w - zz.w;
        lsum += d0 * d0 + d1 * d1 + d2 * d2 + d3 * d3;
    }
    red[t] = lsum;
    __syncthreads();
    for (int s = 128; s > 0; s >>= 1) {
        if (t < s) red[t] += red[t + s];
        __syncthreads();
    }
    if (t == 0) atomicAdd(loss_sum, red[0]);
}

// ---------------------------------------------------------------------------
// Final scalars: loss, perplexity, closed-form mean_distance.
// partialZ/partialC are already fully reduced [256] arrays.
// ---------------------------------------------------------------------------
__global__ void k_scalars(const int* __restrict__ counts,
                          const float* __restrict__ accums,
                          const float* __restrict__ zsq, const float* __restrict__ csq,
                          const float* __restrict__ partialZ,
                          const float* __restrict__ partialC,
                          float* __restrict__ out_tail) {
    __shared__ double redd[256];
    __shared__ float redf[256];
    int t = threadIdx.x;
    double szsq = 0.0, scsq = 0.0;
    for (int n = t; n < NTOK; n += 256) szsq += (double)zsq[n];
    for (int k = t; k < KCB; k += 256) scsq += (double)csq[k];
    float SZ = partialZ[t];
    float SC = partialC[t];
    double total = 8192.0 * szsq + 16384.0 * scsq - 2.0 * (double)SZ * (double)SC;
    redd[t] = total;
    float s = 0.f;
    for (int k = t; k < KCB; k += 256) {
        float e = (float)counts[k] * (1.0f / 16384.0f);
        s += e * logf(e + 1e-10f);
    }
    redf[t] = s;
    __syncthreads();
    for (int st = 128; st > 0; st >>= 1) {
        if (t < st) { redd[t] += redd[t + st]; redf[t] += redf[t + st]; }
        __syncthreads();
    }
    if (t == 0) {
        out_tail[0] = 1.25f * accums[1] / 4194304.0f;
        out_tail[1] = expf(-redf[0]);
        out_tail[2] = (float)(redd[0] / (16384.0 * 8192.0));
    }
}

// ---------------------------------------------------------------------------
extern "C" void kernel_launch(void* const* d_in, const int* in_sizes, int n_in,
                              void* d_out, int out_size, void* d_ws, size_t ws_size,
                              hipStream_t stream) {
    const float* z     = (const float*)d_in[0];   // [2][256][8192]
    const float* emb_w = (const float*)d_in[1];   // [8192][256]
    const float* w1    = (const float*)d_in[2];   // [256][256]
    const float* w2    = (const float*)d_in[3];   // [256][256]
    float* out = (float*)d_out;

    char* w = (char*)d_ws;
    unsigned short* Ahi = (unsigned short*)(w + 0);          //  8,388,608
    unsigned short* Alo = (unsigned short*)(w + 8388608);    //  8,388,608
    unsigned short* Ebf = (unsigned short*)(w + 16777216);   // 12,582,912 (E'; C_t aliases after mlp1)
    unsigned short* Bhi = (unsigned short*)(w + 29360128);   //  4,194,304
    unsigned short* Blo = (unsigned short*)(w + 33554432);   //  4,194,304
    unsigned short* W1s = (unsigned short*)(w + 37748736);   //    393,216
    unsigned short* W2s = (unsigned short*)(w + 38141952);   //    393,216
    float* zsq   = (float*)(w + 38535168);   // 65,536
    float* sA    = (float*)(w + 38666240);   // 65,536
    float* sB    = (float*)(w + 38731776);   // 65,536
    float* csq   = (float*)(w + 38797312);   // 32,768
    float* sC    = (float*)(w + 38862848);   // 32,768
    float* sCl   = (float*)(w + 38895616);   // 32,768
    unsigned long long* packed  = (unsigned long long*)(w + 38928384); // 131,072
    unsigned long long* packed2 = (unsigned long long*)(w + 39059456); // 131,072
    int*   counts = (int*)(w + 39256064);    // 32,768
    float* partialZ = (float*)(w + 39288832); // [256] pre-reduced
    float* partialC = (float*)(w + 39550976); // [256] pre-reduced
    unsigned* tileMaxC  = (unsigned*)(w + 39682048); // 256
    unsigned* tileMaxCl = (unsigned*)(w + 39682304); // 256
    float* accums = (float*)(w + 39682560);  // [1]loss [2]cnt [3]csqmax [4]closqmax

    float* C_t = (float*)Ebf;                        // alias: E' dead after mlp1
    unsigned short* Hs = (unsigned short*)d_out;     // Hs then cand share d_out
    unsigned long long* cand = (unsigned long long*)d_out;

    // prep: splitW + buildA(v2, float4/512blk) + buildE fused
    k_prep<<<3072, 256, 0, stream>>>(w1, w2, W1s, W2s, counts,
                                     tileMaxC, tileMaxCl, accums, partialZ, partialC,
                                     z, Ahi, Alo, zsq, sA, sB, packed, packed2,
                                     emb_w, Ebf);

    // MLP: Hs[k][768] = split(gelu(E' x W1s^T))  (codes on the M side)
    k_mlp<1><<<dim3(2, 128), 256, 0, stream>>>(Ebf, W1s, Hs, nullptr);
    // C_t[d][8192] = W2s x Hs^T
    k_mlp<0><<<dim3(64, 4), 256, 0, stream>>>(W2s, Hs, nullptr, C_t);

    k_buildB<<<KCB / 64, 256, 0, stream>>>(C_t, Bhi, Blo, csq, sC, sCl,
                                           tileMaxC, tileMaxCl, accums, partialC);

    // Phase-1: d_hi GEMM (256x256 tiles, R1 structure, single dispatch)
    k_dist_hi<<<dim3(NTOK / 256, KCB / 256), 512, 0, stream>>>(
        Ahi, Bhi, zsq, csq, sA, sB, tileMaxC, tileMaxCl, packed, accums, cand);

    // Phase-2: two-phase rescore (lane-parallel prefilter + wave rescore)
    k_rescore<<<2048, 256, 0, stream>>>(cand, Ahi, Alo, Bhi, Blo, zsq, csq,
                                        sA, sB, sC, sCl, packed, packed2, accums);

    // zqloss (+fused histogram, evenly spread)
    k_zqloss<<<BATCH * DIM, 256, 0, stream>>>(z, C_t, packed2, out, accums + 1, counts);
    k_scalars<<<1, 256, 0, stream>>>(counts, accums, zsq, csq, partialZ, partialC, out + OUTQ);
}